// Round 16
// baseline (177.467 us; speedup 1.0000x reference)
//
#include <hip/hip_runtime.h>
#include <stdint.h>

typedef unsigned int u32;
typedef unsigned long long u64;
typedef unsigned short u16;
typedef unsigned char u8;

#define BB 8
#define NN 8192
#define CC 80
#define KK 1000
#define NC (NN*CC)            // 655360
#define MAXIDX (NC-1)
#define NMS_THR 0.5f
#define SCORE_THR 0.05f
#define MAX_RATIO 4.135166556742356f
#define CLS_OFF 10000.0f
#define CAP 2048
#define NW 16                 // u64 words per mask row
#define HB 8                  // hist1 sub-blocks per batch (1024 thr each)
#define SGB 128               // stage blocks per batch
#define NTILE 136             // lower-triangle 64x64 tiles
#define TLX 9                 // tail blocks per batch (9*16 waves >= 136 tiles)
#define LBUF 1024             // stage per-block staging buffer (u64)
#define GBUFCAP 98304         // per-batch superset capacity (u64)

#define SC_AGENT __HIP_MEMORY_SCOPE_AGENT

// ---- workspace layout (bytes) ----
#define WS_HIST1   0          // BB*HB*2048*4 = 524288 (private slices, plain stores)
#define WS_HIST2   524288     // BB*2048*4 = 65536 (atomic-accumulated; zeroed by hist1)
#define WS_CTRL    589824     // 16 u32: gcount(8), tick(8)
#define WS_GCOUNT  589824
#define WS_TICK    589856
#define WS_GBUF    589952     // 8*98304*8 = 6291456 -> 6881408
#define WS_MASK    6881408    // 8*16*1000*8 = 1024000 -> 7905408

__device__ __forceinline__ u32 mapf(float f) {
    u32 u = __float_as_uint(f);
    return (u & 0x80000000u) ? ~u : (u | 0x80000000u);
}
__device__ __forceinline__ float unmapf(u32 m) {
    u32 u = (m & 0x80000000u) ? (m ^ 0x80000000u) : ~m;
    return __uint_as_float(u);
}

// ---------------- D1: private 11-bit histograms + fold-in zeroing of control bufs -----
__global__ __launch_bounds__(1024) void hist1_pass(const float* __restrict__ scores,
                                                   u32* __restrict__ hist1,
                                                   u32* __restrict__ hist2,
                                                   u32* __restrict__ ctrl /* 16 u32 */) {
    __shared__ u32 lh[2048];
    int b = blockIdx.y, blk = blockIdx.x, t = threadIdx.x;
    for (int i = t; i < 2048; i += 1024) lh[i] = 0;
    // zero hist2 slice (each of the 64 blocks zeroes 256 u32) and ctrl (block 0,0)
    if (t < 256) hist2[(b * HB + blk) * 256 + t] = 0u;
    else if (t < 272 && b == 0 && blk == 0) ctrl[t - 256] = 0u;
    __syncthreads();
    const float4* sp = (const float4*)(scores + (size_t)b * NC);
    int nvec = NC / 4;
    for (int v = blk * 1024 + t; v < nvec; v += HB * 1024) {
        float4 s4 = sp[v];
        float ss[4] = {s4.x, s4.y, s4.z, s4.w};
        #pragma unroll
        for (int q = 0; q < 4; ++q) {
            float s = ss[q] > SCORE_THR ? ss[q] : -1.0f;
            atomicAdd(&lh[mapf(s) >> 21], 1u);
        }
    }
    __syncthreads();
    u32* ho = hist1 + ((size_t)b * HB + blk) * 2048;
    for (int i = t; i < 2048; i += 1024) ho[i] = lh[i];
}

// ---- fast digit selects: wave shfl suffix-scan, 2 barriers total ----
// 256-thread version, 8 bins/thread (descending). bc[0]=digit, bc[1]=rem.
__device__ __forceinline__ void sel8_fast(const u32 hv[8], u32 need,
                                          u32* wt, u32* wsuf, u32* bc) {
    int t = threadIdx.x, l = t & 63, w = t >> 6;   // 4 waves
    u32 s = 0;
    #pragma unroll
    for (int q = 0; q < 8; ++q) s += hv[q];
    u32 x = s;
    #pragma unroll
    for (int off = 1; off < 64; off <<= 1) {
        u32 y = __shfl_down(x, off);
        if (l + off < 64) x += y;
    }
    if (l == 0) wt[w] = x;
    __syncthreads();
    if (w == 0) {
        u32 v = (l < 4) ? wt[l] : 0u;
        #pragma unroll
        for (int off = 1; off < 4; off <<= 1) {
            u32 y = __shfl_down(v, off);
            if (l + off < 4) v += y;
        }
        if (l < 4) wsuf[l] = v;
    }
    __syncthreads();
    u32 sufAll = x + ((w < 3) ? wsuf[w + 1] : 0u);
    u32 cumAbove = sufAll - s;
    if (cumAbove < need && sufAll >= need) {
        u32 cum = cumAbove;
        int d = t * 8;
        #pragma unroll
        for (int q = 7; q >= 0; --q) {
            if (cum + hv[q] >= need) { d = t * 8 + q; break; }
            cum += hv[q];
        }
        bc[0] = (u32)d;
        bc[1] = need - cum;
    }
    __syncthreads();
}

// 1024-thread version, 2 bins/thread (descending). bc[0]=digit, bc[1]=rem.
__device__ __forceinline__ void sel2_fast(u32 hv0, u32 hv1, u32 need,
                                          u32* wt, u32* wsuf, u32* bc) {
    int t = threadIdx.x, l = t & 63, w = t >> 6;   // 16 waves
    u32 s = hv0 + hv1;
    u32 x = s;
    #pragma unroll
    for (int off = 1; off < 64; off <<= 1) {
        u32 y = __shfl_down(x, off);
        if (l + off < 64) x += y;
    }
    if (l == 0) wt[w] = x;
    __syncthreads();
    if (w == 0) {
        u32 v = (l < 16) ? wt[l] : 0u;
        #pragma unroll
        for (int off = 1; off < 16; off <<= 1) {
            u32 y = __shfl_down(v, off);
            if (l + off < 16) v += y;
        }
        if (l < 16) wsuf[l] = v;
    }
    __syncthreads();
    u32 sufAll = x + ((w < 15) ? wsuf[w + 1] : 0u);
    u32 cumAbove = sufAll - s;
    if (cumAbove < need && sufAll >= need) {
        if (cumAbove + hv1 >= need) { bc[0] = 2u * t + 1u; bc[1] = need - cumAbove; }
        else                        { bc[0] = 2u * t;      bc[1] = need - cumAbove - hv1; }
    }
    __syncthreads();
}

// ---------------- D2: stage d0-superset + build hist2 (bits 20..10 of d0-items) ------
__global__ __launch_bounds__(256) void stage_pass(
    const float* __restrict__ scores, const u32* __restrict__ hist1,
    u32* __restrict__ hist2, u64* __restrict__ gbuf, u32* __restrict__ gcount) {
    __shared__ u64 buf[LBUF];
    __shared__ u32 h2[2048];
    __shared__ u32 wt[4], wsuf[4];
    __shared__ u32 bc[2];
    __shared__ u32 lcnt, lbase;
    int b = blockIdx.y, bx = blockIdx.x, t = threadIdx.x;
    for (int i = t; i < 2048; i += 256) h2[i] = 0;
    if (t == 0) lcnt = 0;
    u32 hv[8];
    {
        const u32* h = hist1 + (size_t)b * HB * 2048;
        #pragma unroll
        for (int q = 0; q < 8; ++q) {
            u32 v = 0;
            #pragma unroll
            for (int sb = 0; sb < HB; ++sb) v += h[sb * 2048 + t * 8 + q];
            hv[q] = v;
        }
    }
    __syncthreads();
    sel8_fast(hv, (u32)KK, wt, wsuf, bc);
    u32 d0 = bc[0];
    const float4* sp = (const float4*)(scores + (size_t)b * NC);
    int nvec = NC / 4;
    for (int v = bx * 256 + t; v < nvec; v += SGB * 256) {
        float4 s4 = sp[v];
        float ss[4] = {s4.x, s4.y, s4.z, s4.w};
        #pragma unroll
        for (int q = 0; q < 4; ++q) {
            float s = ss[q] > SCORE_THR ? ss[q] : -1.0f;
            u32 m = mapf(s);
            u32 top = m >> 21;
            if (top >= d0) {
                u32 p = atomicAdd(&lcnt, 1u);
                if (p < LBUF) {
                    u32 idx = (u32)(v * 4 + q);
                    buf[p] = ((u64)m << 32) | (u64)(MAXIDX - idx);
                }
                if (top == d0) atomicAdd(&h2[(m >> 10) & 0x7FFu], 1u);
            }
        }
    }
    __syncthreads();
    for (int i = t; i < 2048; i += 256)
        if (h2[i]) atomicAdd(&hist2[b * 2048 + i], h2[i]);
    if (t == 0) {
        u32 c = lcnt; if (c > LBUF) c = LBUF;
        lcnt = c;
        lbase = atomicAdd(&gcount[b], c);
    }
    __syncthreads();
    u32 c = lcnt, base = lbase;
    for (u32 i = t; i < c; i += 256) {
        u32 p = base + i;
        if (p < GBUFCAP) gbuf[(size_t)b * GBUFCAP + p] = buf[i];
    }
}

// ---------------- D3: fused tail — filter + rank + decode(LDS) + IoU + NMS + output --
__global__ __launch_bounds__(1024) void tail_pass(
    const u64* __restrict__ gbuf, const u32* __restrict__ gcount,
    const u32* __restrict__ hist1, const u32* __restrict__ hist2,
    const float* __restrict__ rois, const float* __restrict__ reg,
    u64* __restrict__ maskT, u32* __restrict__ tick, float* __restrict__ out) {
    __shared__ u64 keys[CAP];      // 16 KB
    __shared__ u16 rnk[CAP];       // 4 KB
    __shared__ float tb[KK][4];    // 16 KB
    __shared__ float ob[KK][4];    // 16 KB
    __shared__ float ts[KK];       // 4 KB
    __shared__ float tc[KK];       // 4 KB
    __shared__ u8  tv[KK];         // 1 KB
    __shared__ u64 skept[NW];
    __shared__ u32 wt[16], wsuf[16], bc[2];
    __shared__ u32 lcnt;
    __shared__ int islast;
    int b = blockIdx.y, bx = blockIdx.x, t = threadIdx.x;
    int wv = t >> 6, ln = t & 63;  // 16 waves

    if (t == 0) lcnt = 0;
    u32 hv0 = 0, hv1 = 0;
    {
        const u32* h = hist1 + (size_t)b * HB * 2048;
        #pragma unroll
        for (int sb = 0; sb < HB; ++sb) {
            hv0 += h[sb * 2048 + 2 * t];
            hv1 += h[sb * 2048 + 2 * t + 1];
        }
    }
    __syncthreads();
    sel2_fast(hv0, hv1, (u32)KK, wt, wsuf, bc);
    u32 d0 = bc[0], rem = bc[1];
    __syncthreads();
    sel2_fast(hist2[b * 2048 + 2 * t], hist2[b * 2048 + 2 * t + 1], rem, wt, wsuf, bc);
    u32 thr = ((d0 << 11) | bc[0]) << 10;

    // ---- redundant filter: every block builds the full candidate set in LDS ----
    // (order differs per block; rank-by-counting is order-independent -> identical rows)
    u32 cnt = gcount[b]; if (cnt > GBUFCAP) cnt = GBUFCAP;
    const u64* gb = gbuf + (size_t)b * GBUFCAP;
    for (u32 i = t; i < cnt; i += 1024) {
        u64 key = gb[i];
        if ((u32)(key >> 32) >= thr) {
            u32 p = atomicAdd(&lcnt, 1u);
            if (p < CAP) keys[p] = key;
        }
    }
    __syncthreads();
    u32 cnt2 = lcnt; if (cnt2 > CAP) cnt2 = CAP;

    // ---- rank: wave per candidate, lanes split the set, shuffle-reduce ----
    for (u32 ci = wv; ci < cnt2; ci += 16) {
        u64 my = keys[ci];
        u32 cgt = 0;
        for (u32 j = ln; j < cnt2; j += 64)
            cgt += (keys[j] > my) ? 1u : 0u;
        #pragma unroll
        for (int off = 32; off >= 1; off >>= 1)
            cgt += __shfl_down(cgt, off);
        if (ln == 0) rnk[ci] = (u16)cgt;
    }
    __syncthreads();

    // ---- decode all candidates into LDS rows (rank = sorted position) ----
    for (u32 i = t; i < cnt2; i += 1024) {
        u32 r = rnk[i];
        if (r < KK) {
            u64 key = keys[i];
            u32 m = (u32)(key >> 32);
            u32 idx = (u32)MAXIDX - (u32)(key & 0xFFFFFFFFu);
            float score = unmapf(m);
            u8 vld = (score > SCORE_THR) ? 1 : 0;
            int n = idx / CC, c = idx % CC;
            float cf = (float)(c + 1);
            const float* rr = rois + ((size_t)b * NN + n) * 4;
            const float* d  = reg  + ((size_t)b * NN + n) * 4;
            float x1 = rr[0], y1 = rr[1], x2 = rr[2], y2 = rr[3];
            float w = x2 - x1, h = y2 - y1;
            float cx = x1 + 0.5f * w, cy = y1 + 0.5f * h;
            float dx = d[0], dy = d[1];
            float dw = fminf(fmaxf(d[2], -MAX_RATIO), MAX_RATIO);
            float dh = fminf(fmaxf(d[3], -MAX_RATIO), MAX_RATIO);
            float pw = w * expf(dw), ph = h * expf(dh);
            float pcx = cx + dx * w, pcy = cy + dy * h;
            float box0 = pcx - 0.5f * pw, box1 = pcy - 0.5f * ph;
            float box2 = pcx + 0.5f * pw, box3 = pcy + 0.5f * ph;
            tb[r][0] = box0; tb[r][1] = box1; tb[r][2] = box2; tb[r][3] = box3;
            ts[r] = score; tc[r] = cf; tv[r] = vld;
            float off = cf * CLS_OFF;
            ob[r][0] = box0 + off; ob[r][1] = box1 + off;
            ob[r][2] = box2 + off; ob[r][3] = box3 + off;
        }
    }
    // filler rows [cnt2, KK)
    for (u32 r = cnt2 + t; r < KK; r += 1024) {
        ts[r] = -1.0f; tc[r] = 0.0f; tv[r] = 0;
        tb[r][0] = 0; tb[r][1] = 0; tb[r][2] = 0; tb[r][3] = 0;
        ob[r][0] = 0; ob[r][1] = 0; ob[r][2] = 0; ob[r][3] = 0;
    }
    __syncthreads();

    // ---- IoU: one 64x64 lower-triangle tile per wave; T = bx*16 + wv ----
    {
        int T = bx * 16 + wv;
        if (T < NTILE) {
            int ib = (int)((sqrtf(8.0f * (float)T + 1.0f) - 1.0f) * 0.5f);
            while ((ib + 1) * (ib + 2) / 2 <= T) ++ib;
            while (ib * (ib + 1) / 2 > T) --ib;
            int jbk = T - ib * (ib + 1) / 2;
            int i = ib * 64 + ln;
            if (i < KK) {
                float x1 = ob[i][0], y1 = ob[i][1], x2 = ob[i][2], y2 = ob[i][3];
                float ai = (x2 - x1) * (y2 - y1);
                u64 bits = 0;
                int j0 = jbk * 64;
                int jmax = min(64, KK - j0);
                for (int jj = 0; jj < jmax; ++jj) {
                    float bx1 = ob[j0+jj][0], by1 = ob[j0+jj][1];
                    float bx2 = ob[j0+jj][2], by2 = ob[j0+jj][3];
                    float aj = (bx2 - bx1) * (by2 - by1);
                    float iw = fmaxf(fminf(x2, bx2) - fmaxf(x1, bx1), 0.0f);
                    float ih = fmaxf(fminf(y2, by2) - fmaxf(y1, by1), 0.0f);
                    float inter = iw * ih;
                    float iou = inter / (ai + aj - inter + 1e-9f);
                    if (iou > NMS_THR) bits |= (1ull << jj);
                }
                __hip_atomic_store(&maskT[((size_t)b * NW + jbk) * KK + i], bits,
                                   __ATOMIC_RELAXED, SC_AGENT);
            }
        }
    }
    __syncthreads();
    if (t == 0) {
        u32 tk = __hip_atomic_fetch_add(&tick[b], 1u, __ATOMIC_ACQ_REL, SC_AGENT);
        islast = (tk == (u32)(TLX - 1)) ? 1 : 0;
    }
    __syncthreads();
    if (!islast) return;

    // ---- last block: ballot fixed-point NMS (first wave), output from own LDS ----
    if (t < 64) {
        const u64* mT = maskT + (size_t)b * NW * KK;
        u64 keptW[NW];
        #pragma unroll
        for (int W = 0; W < NW; ++W) {
            int i = W * 64 + ln;
            bool inr = (i < KK);
            u64 row[NW];
            #pragma unroll
            for (int w = 0; w <= W; ++w)
                row[w] = inr ? __hip_atomic_load(&mT[(size_t)w * KK + i],
                                                 __ATOMIC_RELAXED, SC_AGENT) : 0ull;
            bool valid = inr && (tv[i] != 0);
            u64 ext = 0;
            #pragma unroll
            for (int w = 0; w < W; ++w) ext |= keptW[w] & row[w];
            bool cand = valid && (ext == 0ull);
            u64 m_self = row[W] & ((1ull << ln) - 1ull);
            u64 kept = __ballot(cand);
            while (true) {
                u64 k2 = __ballot(cand && ((kept & m_self) == 0ull));
                if (k2 == kept) break;
                kept = k2;
            }
            keptW[W] = kept;
            if (ln == 0) skept[W] = kept;
        }
    }
    __syncthreads();
    for (int kk = t; kk < KK; kk += 1024) {
        size_t o = (size_t)b * KK + kk;
        float kf = (float)((skept[kk >> 6] >> (kk & 63)) & 1ull);
        float* op = out + o * 7;
        op[0] = tb[kk][0] * kf; op[1] = tb[kk][1] * kf;
        op[2] = tb[kk][2] * kf; op[3] = tb[kk][3] * kf;
        op[4] = ts[kk] * kf;    op[5] = tc[kk] * kf;    op[6] = kf;
    }
}

extern "C" void kernel_launch(void* const* d_in, const int* in_sizes, int n_in,
                              void* d_out, int out_size, void* d_ws, size_t ws_size,
                              hipStream_t stream) {
    const float* rois   = (const float*)d_in[0];   // (B,N,4)
    const float* scores = (const float*)d_in[1];   // (B*N,C,1,1) == (B, N*C)
    const float* reg    = (const float*)d_in[2];   // (B*N,4,1,1)
    float* out = (float*)d_out;

    char* ws = (char*)d_ws;
    u32* hist1  = (u32*)(ws + WS_HIST1);
    u32* hist2  = (u32*)(ws + WS_HIST2);
    u32* gcount = (u32*)(ws + WS_GCOUNT);
    u32* tick   = (u32*)(ws + WS_TICK);
    u64* gbuf   = (u64*)(ws + WS_GBUF);
    u64* maskT  = (u64*)(ws + WS_MASK);

    hist1_pass<<<dim3(HB, BB), 1024, 0, stream>>>(scores, hist1, hist2, gcount);

    stage_pass<<<dim3(SGB, BB), 256, 0, stream>>>(scores, hist1, hist2, gbuf, gcount);

    tail_pass<<<dim3(TLX, BB), 1024, 0, stream>>>(
        gbuf, gcount, hist1, hist2, rois, reg, maskT, tick, out);
}

// Round 17
// 154.946 us; speedup vs baseline: 1.1454x; 1.1454x over previous
//
#include <hip/hip_runtime.h>
#include <stdint.h>

typedef unsigned int u32;
typedef unsigned long long u64;
typedef unsigned short u16;
typedef unsigned char u8;

#define BB 8
#define NN 8192
#define CC 80
#define KK 1000
#define NC (NN*CC)            // 655360
#define MAXIDX (NC-1)
#define NMS_THR 0.5f
#define SCORE_THR 0.05f
#define MAX_RATIO 4.135166556742356f
#define CLS_OFF 10000.0f
#define CAP 2048
#define NW 16                 // u64 words per mask row
#define HB 8                  // hist1 sub-blocks per batch (1024 thr each)
#define SGB 128               // stage blocks per batch
#define D4X 8                 // refine blocks per batch (1024 thr each)
#define NTILE 136             // lower-triangle 64x64 tiles
#define TLX 9                 // tail blocks per batch (9*16 waves >= 136 tiles)
#define LBUF 1024             // stage per-block staging buffer (u64)
#define GBUFCAP 98304         // per-batch superset capacity (u64)

#define SC_AGENT __HIP_MEMORY_SCOPE_AGENT

// ---- workspace layout (bytes) ----
#define WS_HIST1   0          // BB*HB*2048*4 = 524288 (private slices, plain stores)
#define WS_HIST2   524288     // BB*2048*4 = 65536 (atomic-accumulated; zeroed by hist1)
#define WS_CTRL    589824     // 32 u32: gcount(8), tick(8), gcount2(8), spare(8)
#define WS_GCOUNT  589824
#define WS_TICK    589856
#define WS_GCOUNT2 589888
#define WS_GBUF    589952     // 8*98304*8 = 6291456 -> 6881408
#define WS_GBUF2   6881408    // 8*2048*8 = 131072 -> 7012480
#define WS_MASK    7012480    // 8*16*1000*8 = 1024000 -> 8036480

__device__ __forceinline__ u32 mapf(float f) {
    u32 u = __float_as_uint(f);
    return (u & 0x80000000u) ? ~u : (u | 0x80000000u);
}
__device__ __forceinline__ float unmapf(u32 m) {
    u32 u = (m & 0x80000000u) ? (m ^ 0x80000000u) : ~m;
    return __uint_as_float(u);
}

// ---------------- D1: private 11-bit histograms + fold-in zeroing of control bufs -----
__global__ __launch_bounds__(1024) void hist1_pass(const float* __restrict__ scores,
                                                   u32* __restrict__ hist1,
                                                   u32* __restrict__ hist2,
                                                   u32* __restrict__ ctrl /* 32 u32 */) {
    __shared__ u32 lh[2048];
    int b = blockIdx.y, blk = blockIdx.x, t = threadIdx.x;
    for (int i = t; i < 2048; i += 1024) lh[i] = 0;
    // zero hist2 slice (each of the 64 blocks zeroes 256 u32) and ctrl (block 0,0)
    if (t < 256) hist2[(b * HB + blk) * 256 + t] = 0u;
    else if (t < 288 && b == 0 && blk == 0) ctrl[t - 256] = 0u;
    __syncthreads();
    const float4* sp = (const float4*)(scores + (size_t)b * NC);
    int nvec = NC / 4;
    for (int v = blk * 1024 + t; v < nvec; v += HB * 1024) {
        float4 s4 = sp[v];
        float ss[4] = {s4.x, s4.y, s4.z, s4.w};
        #pragma unroll
        for (int q = 0; q < 4; ++q) {
            float s = ss[q] > SCORE_THR ? ss[q] : -1.0f;
            atomicAdd(&lh[mapf(s) >> 21], 1u);
        }
    }
    __syncthreads();
    u32* ho = hist1 + ((size_t)b * HB + blk) * 2048;
    for (int i = t; i < 2048; i += 1024) ho[i] = lh[i];
}

// ---- fast digit selects: wave shfl suffix-scan, 2 barriers total ----
// 256-thread version, 8 bins/thread (descending). bc[0]=digit, bc[1]=rem.
__device__ __forceinline__ void sel8_fast(const u32 hv[8], u32 need,
                                          u32* wt, u32* wsuf, u32* bc) {
    int t = threadIdx.x, l = t & 63, w = t >> 6;   // 4 waves
    u32 s = 0;
    #pragma unroll
    for (int q = 0; q < 8; ++q) s += hv[q];
    u32 x = s;
    #pragma unroll
    for (int off = 1; off < 64; off <<= 1) {
        u32 y = __shfl_down(x, off);
        if (l + off < 64) x += y;
    }
    if (l == 0) wt[w] = x;
    __syncthreads();
    if (w == 0) {
        u32 v = (l < 4) ? wt[l] : 0u;
        #pragma unroll
        for (int off = 1; off < 4; off <<= 1) {
            u32 y = __shfl_down(v, off);
            if (l + off < 4) v += y;
        }
        if (l < 4) wsuf[l] = v;
    }
    __syncthreads();
    u32 sufAll = x + ((w < 3) ? wsuf[w + 1] : 0u);
    u32 cumAbove = sufAll - s;
    if (cumAbove < need && sufAll >= need) {
        u32 cum = cumAbove;
        int d = t * 8;
        #pragma unroll
        for (int q = 7; q >= 0; --q) {
            if (cum + hv[q] >= need) { d = t * 8 + q; break; }
            cum += hv[q];
        }
        bc[0] = (u32)d;
        bc[1] = need - cum;
    }
    __syncthreads();
}

// 1024-thread version, 2 bins/thread (descending). bc[0]=digit, bc[1]=rem.
__device__ __forceinline__ void sel2_fast(u32 hv0, u32 hv1, u32 need,
                                          u32* wt, u32* wsuf, u32* bc) {
    int t = threadIdx.x, l = t & 63, w = t >> 6;   // 16 waves
    u32 s = hv0 + hv1;
    u32 x = s;
    #pragma unroll
    for (int off = 1; off < 64; off <<= 1) {
        u32 y = __shfl_down(x, off);
        if (l + off < 64) x += y;
    }
    if (l == 0) wt[w] = x;
    __syncthreads();
    if (w == 0) {
        u32 v = (l < 16) ? wt[l] : 0u;
        #pragma unroll
        for (int off = 1; off < 16; off <<= 1) {
            u32 y = __shfl_down(v, off);
            if (l + off < 16) v += y;
        }
        if (l < 16) wsuf[l] = v;
    }
    __syncthreads();
    u32 sufAll = x + ((w < 15) ? wsuf[w + 1] : 0u);
    u32 cumAbove = sufAll - s;
    if (cumAbove < need && sufAll >= need) {
        if (cumAbove + hv1 >= need) { bc[0] = 2u * t + 1u; bc[1] = need - cumAbove; }
        else                        { bc[0] = 2u * t;      bc[1] = need - cumAbove - hv1; }
    }
    __syncthreads();
}

// ---------------- D2: stage d0-superset + build hist2 (bits 20..10 of d0-items) ------
__global__ __launch_bounds__(256) void stage_pass(
    const float* __restrict__ scores, const u32* __restrict__ hist1,
    u32* __restrict__ hist2, u64* __restrict__ gbuf, u32* __restrict__ gcount) {
    __shared__ u64 buf[LBUF];
    __shared__ u32 h2[2048];
    __shared__ u32 wt[4], wsuf[4];
    __shared__ u32 bc[2];
    __shared__ u32 lcnt, lbase;
    int b = blockIdx.y, bx = blockIdx.x, t = threadIdx.x;
    for (int i = t; i < 2048; i += 256) h2[i] = 0;
    if (t == 0) lcnt = 0;
    u32 hv[8];
    {
        const u32* h = hist1 + (size_t)b * HB * 2048;
        #pragma unroll
        for (int q = 0; q < 8; ++q) {
            u32 v = 0;
            #pragma unroll
            for (int sb = 0; sb < HB; ++sb) v += h[sb * 2048 + t * 8 + q];
            hv[q] = v;
        }
    }
    __syncthreads();
    sel8_fast(hv, (u32)KK, wt, wsuf, bc);
    u32 d0 = bc[0];
    const float4* sp = (const float4*)(scores + (size_t)b * NC);
    int nvec = NC / 4;
    for (int v = bx * 256 + t; v < nvec; v += SGB * 256) {
        float4 s4 = sp[v];
        float ss[4] = {s4.x, s4.y, s4.z, s4.w};
        #pragma unroll
        for (int q = 0; q < 4; ++q) {
            float s = ss[q] > SCORE_THR ? ss[q] : -1.0f;
            u32 m = mapf(s);
            u32 top = m >> 21;
            if (top >= d0) {
                u32 p = atomicAdd(&lcnt, 1u);
                if (p < LBUF) {
                    u32 idx = (u32)(v * 4 + q);
                    buf[p] = ((u64)m << 32) | (u64)(MAXIDX - idx);
                }
                if (top == d0) atomicAdd(&h2[(m >> 10) & 0x7FFu], 1u);
            }
        }
    }
    __syncthreads();
    for (int i = t; i < 2048; i += 256)
        if (h2[i]) atomicAdd(&hist2[b * 2048 + i], h2[i]);
    if (t == 0) {
        u32 c = lcnt; if (c > LBUF) c = LBUF;
        lcnt = c;
        lbase = atomicAdd(&gcount[b], c);
    }
    __syncthreads();
    u32 c = lcnt, base = lbase;
    for (u32 i = t; i < c; i += 256) {
        u32 p = base + i;
        if (p < GBUFCAP) gbuf[(size_t)b * GBUFCAP + p] = buf[i];
    }
}

// ---------------- D3: exact 22-bit filter of staged superset -> gbuf2 (compaction) ---
__global__ __launch_bounds__(1024) void refine_pass(
    const u64* __restrict__ gbuf, const u32* __restrict__ gcount,
    const u32* __restrict__ hist1, const u32* __restrict__ hist2,
    u64* __restrict__ gbuf2, u32* __restrict__ gcount2) {
    __shared__ u64 keys[CAP];
    __shared__ u32 wt[16], wsuf[16];
    __shared__ u32 bc[2];
    __shared__ u32 lcnt, lbase;
    int b = blockIdx.y, bx = blockIdx.x, t = threadIdx.x;
    if (t == 0) lcnt = 0;
    u32 hv0 = 0, hv1 = 0;
    {
        const u32* h = hist1 + (size_t)b * HB * 2048;
        #pragma unroll
        for (int sb = 0; sb < HB; ++sb) {
            hv0 += h[sb * 2048 + 2 * t];
            hv1 += h[sb * 2048 + 2 * t + 1];
        }
    }
    __syncthreads();
    sel2_fast(hv0, hv1, (u32)KK, wt, wsuf, bc);
    u32 d0 = bc[0], rem = bc[1];
    __syncthreads();
    sel2_fast(hist2[b * 2048 + 2 * t], hist2[b * 2048 + 2 * t + 1], rem, wt, wsuf, bc);
    u32 thr = ((d0 << 11) | bc[0]) << 10;

    u32 cnt = gcount[b]; if (cnt > GBUFCAP) cnt = GBUFCAP;
    const u64* gb = gbuf + (size_t)b * GBUFCAP;
    u32 chunk = (cnt + D4X - 1) / D4X;
    u32 lo = bx * chunk, hi = lo + chunk; if (hi > cnt) hi = cnt;
    for (u32 i = lo + t; i < hi; i += 1024) {
        u64 key = gb[i];
        if ((u32)(key >> 32) >= thr) {
            u32 p = atomicAdd(&lcnt, 1u);
            if (p < CAP) keys[p] = key;
        }
    }
    __syncthreads();
    if (t == 0) {
        u32 c = lcnt; if (c > CAP) c = CAP;
        lcnt = c;
        lbase = atomicAdd(&gcount2[b], c);      // default atomicAdd = device scope
    }
    __syncthreads();
    u32 c = lcnt, base = lbase;
    for (u32 i = t; i < c; i += 1024) {
        u32 p = base + i;
        if (p < CAP) gbuf2[(size_t)b * CAP + p] = keys[i];   // plain stores
    }
}

// ---------------- D4: fused tail from COMPACT set — rank+decode(LDS)+IoU+NMS+output --
__global__ __launch_bounds__(1024) void tail_pass(
    const u64* __restrict__ gbuf2, const u32* __restrict__ gcount2,
    const float* __restrict__ rois, const float* __restrict__ reg,
    u64* __restrict__ maskT, u32* __restrict__ tick, float* __restrict__ out) {
    __shared__ u64 keys[CAP];      // 16 KB
    __shared__ u16 rnk[CAP];       // 4 KB
    __shared__ float tb[KK][4];    // 16 KB
    __shared__ float ob[KK][4];    // 16 KB
    __shared__ float ts[KK];       // 4 KB
    __shared__ float tc[KK];       // 4 KB
    __shared__ u8  tv[KK];         // 1 KB
    __shared__ u64 skept[NW];
    __shared__ int islast;
    int b = blockIdx.y, bx = blockIdx.x, t = threadIdx.x;
    int wv = t >> 6, ln = t & 63;  // 16 waves

    // ---- load compacted candidates (16 KB; identical order for all blocks) ----
    u32 cnt2 = gcount2[b]; if (cnt2 > CAP) cnt2 = CAP;
    for (u32 i = t; i < cnt2; i += 1024)
        keys[i] = gbuf2[(size_t)b * CAP + i];
    __syncthreads();

    // ---- rank: wave per candidate, lanes split the set, shuffle-reduce ----
    for (u32 ci = wv; ci < cnt2; ci += 16) {
        u64 my = keys[ci];
        u32 cgt = 0;
        for (u32 j = ln; j < cnt2; j += 64)
            cgt += (keys[j] > my) ? 1u : 0u;
        #pragma unroll
        for (int off = 32; off >= 1; off >>= 1)
            cgt += __shfl_down(cgt, off);
        if (ln == 0) rnk[ci] = (u16)cgt;
    }
    __syncthreads();

    // ---- decode all candidates into LDS rows (rank = sorted position) ----
    for (u32 i = t; i < cnt2; i += 1024) {
        u32 r = rnk[i];
        if (r < KK) {
            u64 key = keys[i];
            u32 m = (u32)(key >> 32);
            u32 idx = (u32)MAXIDX - (u32)(key & 0xFFFFFFFFu);
            float score = unmapf(m);
            u8 vld = (score > SCORE_THR) ? 1 : 0;
            int n = idx / CC, c = idx % CC;
            float cf = (float)(c + 1);
            const float* rr = rois + ((size_t)b * NN + n) * 4;
            const float* d  = reg  + ((size_t)b * NN + n) * 4;
            float x1 = rr[0], y1 = rr[1], x2 = rr[2], y2 = rr[3];
            float w = x2 - x1, h = y2 - y1;
            float cx = x1 + 0.5f * w, cy = y1 + 0.5f * h;
            float dx = d[0], dy = d[1];
            float dw = fminf(fmaxf(d[2], -MAX_RATIO), MAX_RATIO);
            float dh = fminf(fmaxf(d[3], -MAX_RATIO), MAX_RATIO);
            float pw = w * expf(dw), ph = h * expf(dh);
            float pcx = cx + dx * w, pcy = cy + dy * h;
            float box0 = pcx - 0.5f * pw, box1 = pcy - 0.5f * ph;
            float box2 = pcx + 0.5f * pw, box3 = pcy + 0.5f * ph;
            tb[r][0] = box0; tb[r][1] = box1; tb[r][2] = box2; tb[r][3] = box3;
            ts[r] = score; tc[r] = cf; tv[r] = vld;
            float off = cf * CLS_OFF;
            ob[r][0] = box0 + off; ob[r][1] = box1 + off;
            ob[r][2] = box2 + off; ob[r][3] = box3 + off;
        }
    }
    // filler rows [cnt2, KK)
    for (u32 r = cnt2 + t; r < KK; r += 1024) {
        ts[r] = -1.0f; tc[r] = 0.0f; tv[r] = 0;
        tb[r][0] = 0; tb[r][1] = 0; tb[r][2] = 0; tb[r][3] = 0;
        ob[r][0] = 0; ob[r][1] = 0; ob[r][2] = 0; ob[r][3] = 0;
    }
    __syncthreads();

    // ---- IoU: one 64x64 lower-triangle tile per wave; T = bx*16 + wv ----
    {
        int T = bx * 16 + wv;
        if (T < NTILE) {
            int ib = (int)((sqrtf(8.0f * (float)T + 1.0f) - 1.0f) * 0.5f);
            while ((ib + 1) * (ib + 2) / 2 <= T) ++ib;
            while (ib * (ib + 1) / 2 > T) --ib;
            int jbk = T - ib * (ib + 1) / 2;
            int i = ib * 64 + ln;
            if (i < KK) {
                float x1 = ob[i][0], y1 = ob[i][1], x2 = ob[i][2], y2 = ob[i][3];
                float ai = (x2 - x1) * (y2 - y1);
                u64 bits = 0;
                int j0 = jbk * 64;
                int jmax = min(64, KK - j0);
                for (int jj = 0; jj < jmax; ++jj) {
                    float bx1 = ob[j0+jj][0], by1 = ob[j0+jj][1];
                    float bx2 = ob[j0+jj][2], by2 = ob[j0+jj][3];
                    float aj = (bx2 - bx1) * (by2 - by1);
                    float iw = fmaxf(fminf(x2, bx2) - fmaxf(x1, bx1), 0.0f);
                    float ih = fmaxf(fminf(y2, by2) - fmaxf(y1, by1), 0.0f);
                    float inter = iw * ih;
                    float iou = inter / (ai + aj - inter + 1e-9f);
                    if (iou > NMS_THR) bits |= (1ull << jj);
                }
                __hip_atomic_store(&maskT[((size_t)b * NW + jbk) * KK + i], bits,
                                   __ATOMIC_RELAXED, SC_AGENT);
            }
        }
    }
    __syncthreads();
    if (t == 0) {
        u32 tk = __hip_atomic_fetch_add(&tick[b], 1u, __ATOMIC_ACQ_REL, SC_AGENT);
        islast = (tk == (u32)(TLX - 1)) ? 1 : 0;
    }
    __syncthreads();
    if (!islast) return;

    // ---- last block: ballot fixed-point NMS (first wave), output from own LDS ----
    if (t < 64) {
        const u64* mT = maskT + (size_t)b * NW * KK;
        u64 keptW[NW];
        #pragma unroll
        for (int W = 0; W < NW; ++W) {
            int i = W * 64 + ln;
            bool inr = (i < KK);
            u64 row[NW];
            #pragma unroll
            for (int w = 0; w <= W; ++w)
                row[w] = inr ? __hip_atomic_load(&mT[(size_t)w * KK + i],
                                                 __ATOMIC_RELAXED, SC_AGENT) : 0ull;
            bool valid = inr && (tv[i] != 0);
            u64 ext = 0;
            #pragma unroll
            for (int w = 0; w < W; ++w) ext |= keptW[w] & row[w];
            bool cand = valid && (ext == 0ull);
            u64 m_self = row[W] & ((1ull << ln) - 1ull);
            u64 kept = __ballot(cand);
            while (true) {
                u64 k2 = __ballot(cand && ((kept & m_self) == 0ull));
                if (k2 == kept) break;
                kept = k2;
            }
            keptW[W] = kept;
            if (ln == 0) skept[W] = kept;
        }
    }
    __syncthreads();
    for (int kk = t; kk < KK; kk += 1024) {
        size_t o = (size_t)b * KK + kk;
        float kf = (float)((skept[kk >> 6] >> (kk & 63)) & 1ull);
        float* op = out + o * 7;
        op[0] = tb[kk][0] * kf; op[1] = tb[kk][1] * kf;
        op[2] = tb[kk][2] * kf; op[3] = tb[kk][3] * kf;
        op[4] = ts[kk] * kf;    op[5] = tc[kk] * kf;    op[6] = kf;
    }
}

extern "C" void kernel_launch(void* const* d_in, const int* in_sizes, int n_in,
                              void* d_out, int out_size, void* d_ws, size_t ws_size,
                              hipStream_t stream) {
    const float* rois   = (const float*)d_in[0];   // (B,N,4)
    const float* scores = (const float*)d_in[1];   // (B*N,C,1,1) == (B, N*C)
    const float* reg    = (const float*)d_in[2];   // (B*N,4,1,1)
    float* out = (float*)d_out;

    char* ws = (char*)d_ws;
    u32* hist1   = (u32*)(ws + WS_HIST1);
    u32* hist2   = (u32*)(ws + WS_HIST2);
    u32* gcount  = (u32*)(ws + WS_GCOUNT);
    u32* tick    = (u32*)(ws + WS_TICK);
    u32* gcount2 = (u32*)(ws + WS_GCOUNT2);
    u64* gbuf    = (u64*)(ws + WS_GBUF);
    u64* gbuf2   = (u64*)(ws + WS_GBUF2);
    u64* maskT   = (u64*)(ws + WS_MASK);

    hist1_pass<<<dim3(HB, BB), 1024, 0, stream>>>(scores, hist1, hist2, gcount);

    stage_pass<<<dim3(SGB, BB), 256, 0, stream>>>(scores, hist1, hist2, gbuf, gcount);

    refine_pass<<<dim3(D4X, BB), 1024, 0, stream>>>(
        gbuf, gcount, hist1, hist2, gbuf2, gcount2);

    tail_pass<<<dim3(TLX, BB), 1024, 0, stream>>>(
        gbuf2, gcount2, rois, reg, maskT, tick, out);
}

// Round 18
// 119.301 us; speedup vs baseline: 1.4876x; 1.2988x over previous
//
#include <hip/hip_runtime.h>
#include <stdint.h>

typedef unsigned int u32;
typedef unsigned long long u64;
typedef unsigned short u16;
typedef unsigned char u8;

#define BB 8
#define NN 8192
#define CC 80
#define KK 1000
#define NC (NN*CC)            // 655360
#define MAXIDX (NC-1)
#define NMS_THR 0.5f
#define SCORE_THR 0.05f
#define MAX_RATIO 4.135166556742356f
#define CLS_OFF 10000.0f
#define CAP 2048
#define NW 16                 // u64 words per mask row
#define HB 8                  // hist1 sub-blocks per batch (1024 thr each)
#define SGB 128               // stage blocks per batch
#define D4X 8                 // refine blocks per batch (1024 thr each)
#define NTILE 136             // lower-triangle 64x64 tiles
#define TLX 9                 // tail blocks per batch (9*16 waves >= 136 tiles)
#define LBUF 1024             // stage per-block staging buffer (u64)
#define GBUFCAP 98304         // per-batch superset capacity (u64)

#define SC_AGENT __HIP_MEMORY_SCOPE_AGENT

// ---- workspace layout (bytes) ----
#define WS_HIST1   0          // BB*HB*2048*4 = 524288 (private slices, plain stores)
#define WS_HIST2   524288     // BB*2048*4 = 65536 (atomic-accumulated; zeroed by hist1)
#define WS_CTRL    589824     // 32 u32: gcount(8), tick(8), gcount2(8), spare(8)
#define WS_GCOUNT  589824
#define WS_TICK    589856
#define WS_GCOUNT2 589888
#define WS_GBUF    589952     // 8*98304*8 = 6291456 -> 6881408
#define WS_GBUF2   6881408    // 8*2048*8 = 131072 -> 7012480
#define WS_MASK    7012480    // 8*16*1000*8 = 1024000 -> 8036480

__device__ __forceinline__ u32 mapf(float f) {
    u32 u = __float_as_uint(f);
    return (u & 0x80000000u) ? ~u : (u | 0x80000000u);
}
__device__ __forceinline__ float unmapf(u32 m) {
    u32 u = (m & 0x80000000u) ? (m ^ 0x80000000u) : ~m;
    return __uint_as_float(u);
}

// ---------------- D1: private 11-bit histograms + fold-in zeroing of control bufs -----
__global__ __launch_bounds__(1024) void hist1_pass(const float* __restrict__ scores,
                                                   u32* __restrict__ hist1,
                                                   u32* __restrict__ hist2,
                                                   u32* __restrict__ ctrl /* 32 u32 */) {
    __shared__ u32 lh[2048];
    int b = blockIdx.y, blk = blockIdx.x, t = threadIdx.x;
    for (int i = t; i < 2048; i += 1024) lh[i] = 0;
    // zero hist2 slice (each of the 64 blocks zeroes 256 u32) and ctrl (block 0,0)
    if (t < 256) hist2[(b * HB + blk) * 256 + t] = 0u;
    else if (t < 288 && b == 0 && blk == 0) ctrl[t - 256] = 0u;
    __syncthreads();
    const float4* sp = (const float4*)(scores + (size_t)b * NC);
    int nvec = NC / 4;
    for (int v = blk * 1024 + t; v < nvec; v += HB * 1024) {
        float4 s4 = sp[v];
        float ss[4] = {s4.x, s4.y, s4.z, s4.w};
        #pragma unroll
        for (int q = 0; q < 4; ++q) {
            float s = ss[q] > SCORE_THR ? ss[q] : -1.0f;
            atomicAdd(&lh[mapf(s) >> 21], 1u);
        }
    }
    __syncthreads();
    u32* ho = hist1 + ((size_t)b * HB + blk) * 2048;
    for (int i = t; i < 2048; i += 1024) ho[i] = lh[i];
}

// ---- fast digit selects: wave shfl suffix-scan, 2 barriers total ----
// 256-thread version, 8 bins/thread (descending). bc[0]=digit, bc[1]=rem.
__device__ __forceinline__ void sel8_fast(const u32 hv[8], u32 need,
                                          u32* wt, u32* wsuf, u32* bc) {
    int t = threadIdx.x, l = t & 63, w = t >> 6;   // 4 waves
    u32 s = 0;
    #pragma unroll
    for (int q = 0; q < 8; ++q) s += hv[q];
    u32 x = s;
    #pragma unroll
    for (int off = 1; off < 64; off <<= 1) {
        u32 y = __shfl_down(x, off);
        if (l + off < 64) x += y;
    }
    if (l == 0) wt[w] = x;
    __syncthreads();
    if (w == 0) {
        u32 v = (l < 4) ? wt[l] : 0u;
        #pragma unroll
        for (int off = 1; off < 4; off <<= 1) {
            u32 y = __shfl_down(v, off);
            if (l + off < 4) v += y;
        }
        if (l < 4) wsuf[l] = v;
    }
    __syncthreads();
    u32 sufAll = x + ((w < 3) ? wsuf[w + 1] : 0u);
    u32 cumAbove = sufAll - s;
    if (cumAbove < need && sufAll >= need) {
        u32 cum = cumAbove;
        int d = t * 8;
        #pragma unroll
        for (int q = 7; q >= 0; --q) {
            if (cum + hv[q] >= need) { d = t * 8 + q; break; }
            cum += hv[q];
        }
        bc[0] = (u32)d;
        bc[1] = need - cum;
    }
    __syncthreads();
}

// 1024-thread version, 2 bins/thread (descending). bc[0]=digit, bc[1]=rem.
__device__ __forceinline__ void sel2_fast(u32 hv0, u32 hv1, u32 need,
                                          u32* wt, u32* wsuf, u32* bc) {
    int t = threadIdx.x, l = t & 63, w = t >> 6;   // 16 waves
    u32 s = hv0 + hv1;
    u32 x = s;
    #pragma unroll
    for (int off = 1; off < 64; off <<= 1) {
        u32 y = __shfl_down(x, off);
        if (l + off < 64) x += y;
    }
    if (l == 0) wt[w] = x;
    __syncthreads();
    if (w == 0) {
        u32 v = (l < 16) ? wt[l] : 0u;
        #pragma unroll
        for (int off = 1; off < 16; off <<= 1) {
            u32 y = __shfl_down(v, off);
            if (l + off < 16) v += y;
        }
        if (l < 16) wsuf[l] = v;
    }
    __syncthreads();
    u32 sufAll = x + ((w < 15) ? wsuf[w + 1] : 0u);
    u32 cumAbove = sufAll - s;
    if (cumAbove < need && sufAll >= need) {
        if (cumAbove + hv1 >= need) { bc[0] = 2u * t + 1u; bc[1] = need - cumAbove; }
        else                        { bc[0] = 2u * t;      bc[1] = need - cumAbove - hv1; }
    }
    __syncthreads();
}

// ---------------- D2: stage d0-superset + build hist2 (bits 20..10 of d0-items) ------
__global__ __launch_bounds__(256) void stage_pass(
    const float* __restrict__ scores, const u32* __restrict__ hist1,
    u32* __restrict__ hist2, u64* __restrict__ gbuf, u32* __restrict__ gcount) {
    __shared__ u64 buf[LBUF];
    __shared__ u32 h2[2048];
    __shared__ u32 wt[4], wsuf[4];
    __shared__ u32 bc[2];
    __shared__ u32 lcnt, lbase;
    int b = blockIdx.y, bx = blockIdx.x, t = threadIdx.x;
    for (int i = t; i < 2048; i += 256) h2[i] = 0;
    if (t == 0) lcnt = 0;
    u32 hv[8];
    {
        const u32* h = hist1 + (size_t)b * HB * 2048;
        #pragma unroll
        for (int q = 0; q < 8; ++q) {
            u32 v = 0;
            #pragma unroll
            for (int sb = 0; sb < HB; ++sb) v += h[sb * 2048 + t * 8 + q];
            hv[q] = v;
        }
    }
    __syncthreads();
    sel8_fast(hv, (u32)KK, wt, wsuf, bc);
    u32 d0 = bc[0];
    const float4* sp = (const float4*)(scores + (size_t)b * NC);
    int nvec = NC / 4;
    for (int v = bx * 256 + t; v < nvec; v += SGB * 256) {
        float4 s4 = sp[v];
        float ss[4] = {s4.x, s4.y, s4.z, s4.w};
        #pragma unroll
        for (int q = 0; q < 4; ++q) {
            float s = ss[q] > SCORE_THR ? ss[q] : -1.0f;
            u32 m = mapf(s);
            u32 top = m >> 21;
            if (top >= d0) {
                u32 p = atomicAdd(&lcnt, 1u);
                if (p < LBUF) {
                    u32 idx = (u32)(v * 4 + q);
                    buf[p] = ((u64)m << 32) | (u64)(MAXIDX - idx);
                }
                if (top == d0) atomicAdd(&h2[(m >> 10) & 0x7FFu], 1u);
            }
        }
    }
    __syncthreads();
    for (int i = t; i < 2048; i += 256)
        if (h2[i]) atomicAdd(&hist2[b * 2048 + i], h2[i]);
    if (t == 0) {
        u32 c = lcnt; if (c > LBUF) c = LBUF;
        lcnt = c;
        lbase = atomicAdd(&gcount[b], c);
    }
    __syncthreads();
    u32 c = lcnt, base = lbase;
    for (u32 i = t; i < c; i += 256) {
        u32 p = base + i;
        if (p < GBUFCAP) gbuf[(size_t)b * GBUFCAP + p] = buf[i];
    }
}

// ---------------- D3: exact 22-bit filter of staged superset -> gbuf2 (compaction) ---
__global__ __launch_bounds__(1024) void refine_pass(
    const u64* __restrict__ gbuf, const u32* __restrict__ gcount,
    const u32* __restrict__ hist1, const u32* __restrict__ hist2,
    u64* __restrict__ gbuf2, u32* __restrict__ gcount2) {
    __shared__ u64 keys[CAP];
    __shared__ u32 wt[16], wsuf[16];
    __shared__ u32 bc[2];
    __shared__ u32 lcnt, lbase;
    int b = blockIdx.y, bx = blockIdx.x, t = threadIdx.x;
    if (t == 0) lcnt = 0;
    u32 hv0 = 0, hv1 = 0;
    {
        const u32* h = hist1 + (size_t)b * HB * 2048;
        #pragma unroll
        for (int sb = 0; sb < HB; ++sb) {
            hv0 += h[sb * 2048 + 2 * t];
            hv1 += h[sb * 2048 + 2 * t + 1];
        }
    }
    __syncthreads();
    sel2_fast(hv0, hv1, (u32)KK, wt, wsuf, bc);
    u32 d0 = bc[0], rem = bc[1];
    __syncthreads();
    sel2_fast(hist2[b * 2048 + 2 * t], hist2[b * 2048 + 2 * t + 1], rem, wt, wsuf, bc);
    u32 thr = ((d0 << 11) | bc[0]) << 10;

    u32 cnt = gcount[b]; if (cnt > GBUFCAP) cnt = GBUFCAP;
    const u64* gb = gbuf + (size_t)b * GBUFCAP;
    u32 chunk = (cnt + D4X - 1) / D4X;
    u32 lo = bx * chunk, hi = lo + chunk; if (hi > cnt) hi = cnt;
    for (u32 i = lo + t; i < hi; i += 1024) {
        u64 key = gb[i];
        if ((u32)(key >> 32) >= thr) {
            u32 p = atomicAdd(&lcnt, 1u);
            if (p < CAP) keys[p] = key;
        }
    }
    __syncthreads();
    if (t == 0) {
        u32 c = lcnt; if (c > CAP) c = CAP;
        lcnt = c;
        lbase = atomicAdd(&gcount2[b], c);      // default atomicAdd = device scope
    }
    __syncthreads();
    u32 c = lcnt, base = lbase;
    for (u32 i = t; i < c; i += 1024) {
        u32 p = base + i;
        if (p < CAP) gbuf2[(size_t)b * CAP + p] = keys[i];   // plain stores
    }
}

// decode one key into the LDS tables at row r
__device__ __forceinline__ void decode_lds(
    int b, u32 r, u64 key,
    const float* __restrict__ rois, const float* __restrict__ reg,
    float (*tb)[4], float (*ob)[4], float* ts, float* tc, u8* tv) {
    u32 m = (u32)(key >> 32);
    u32 idx = (u32)MAXIDX - (u32)(key & 0xFFFFFFFFu);
    float score = unmapf(m);
    u8 vld = (score > SCORE_THR) ? 1 : 0;
    int n = idx / CC, c = idx % CC;
    float cf = (float)(c + 1);
    const float* rr = rois + ((size_t)b * NN + n) * 4;
    const float* d  = reg  + ((size_t)b * NN + n) * 4;
    float x1 = rr[0], y1 = rr[1], x2 = rr[2], y2 = rr[3];
    float w = x2 - x1, h = y2 - y1;
    float cx = x1 + 0.5f * w, cy = y1 + 0.5f * h;
    float dx = d[0], dy = d[1];
    float dw = fminf(fmaxf(d[2], -MAX_RATIO), MAX_RATIO);
    float dh = fminf(fmaxf(d[3], -MAX_RATIO), MAX_RATIO);
    float pw = w * expf(dw), ph = h * expf(dh);
    float pcx = cx + dx * w, pcy = cy + dy * h;
    float box0 = pcx - 0.5f * pw, box1 = pcy - 0.5f * ph;
    float box2 = pcx + 0.5f * pw, box3 = pcy + 0.5f * ph;
    tb[r][0] = box0; tb[r][1] = box1; tb[r][2] = box2; tb[r][3] = box3;
    ts[r] = score; tc[r] = cf; tv[r] = vld;
    float off = cf * CLS_OFF;
    ob[r][0] = box0 + off; ob[r][1] = box1 + off;
    ob[r][2] = box2 + off; ob[r][3] = box3 + off;
}

// ---------------- D4: fused tail — broadcast-rank + decode(LDS) + IoU + NMS + output -
__global__ __launch_bounds__(1024) void tail_pass(
    const u64* __restrict__ gbuf2, const u32* __restrict__ gcount2,
    const float* __restrict__ rois, const float* __restrict__ reg,
    u64* __restrict__ maskT, u32* __restrict__ tick, float* __restrict__ out) {
    __shared__ u64 keys[CAP];      // 16 KB
    __shared__ float tb[KK][4];    // 16 KB
    __shared__ float ob[KK][4];    // 16 KB
    __shared__ float ts[KK];       // 4 KB
    __shared__ float tc[KK];       // 4 KB
    __shared__ u8  tv[KK];         // 1 KB
    __shared__ u64 skept[NW];
    __shared__ int islast;
    int b = blockIdx.y, bx = blockIdx.x, t = threadIdx.x;
    int wv = t >> 6, ln = t & 63;  // 16 waves

    // ---- load compacted candidates (16 KB; identical order for all blocks) ----
    u32 cnt2 = gcount2[b]; if (cnt2 > CAP) cnt2 = CAP;
    for (u32 i = t; i < cnt2; i += 1024)
        keys[i] = gbuf2[(size_t)b * CAP + i];
    __syncthreads();

    // ---- rank: thread-per-candidate (2 statically), broadcast j-loop ----
    // every lane in a wave reads the SAME keys[j] per step -> conflict-free broadcast
    u32 c0 = t, c1 = t + 1024;
    bool h0 = (c0 < cnt2), h1 = (c1 < cnt2);
    u64 my0 = h0 ? keys[c0] : 0ull;
    u64 my1 = h1 ? keys[c1] : 0ull;
    u32 r0 = 0, r1 = 0;
    for (u32 j = 0; j < cnt2; ++j) {
        u64 kj = keys[j];
        r0 += (kj > my0) ? 1u : 0u;
        r1 += (kj > my1) ? 1u : 0u;
    }
    // decode immediately (rank held in register; ranks unique -> rows unique)
    if (h0 && r0 < KK) decode_lds(b, r0, my0, rois, reg, tb, ob, ts, tc, tv);
    if (h1 && r1 < KK) decode_lds(b, r1, my1, rois, reg, tb, ob, ts, tc, tv);
    // filler rows [cnt2, KK)
    for (u32 r = cnt2 + t; r < KK; r += 1024) {
        ts[r] = -1.0f; tc[r] = 0.0f; tv[r] = 0;
        tb[r][0] = 0; tb[r][1] = 0; tb[r][2] = 0; tb[r][3] = 0;
        ob[r][0] = 0; ob[r][1] = 0; ob[r][2] = 0; ob[r][3] = 0;
    }
    __syncthreads();

    // ---- IoU: one 64x64 lower-triangle tile per wave; T = bx*16 + wv ----
    {
        int T = bx * 16 + wv;
        if (T < NTILE) {
            int ib = (int)((sqrtf(8.0f * (float)T + 1.0f) - 1.0f) * 0.5f);
            while ((ib + 1) * (ib + 2) / 2 <= T) ++ib;
            while (ib * (ib + 1) / 2 > T) --ib;
            int jbk = T - ib * (ib + 1) / 2;
            int i = ib * 64 + ln;
            if (i < KK) {
                float x1 = ob[i][0], y1 = ob[i][1], x2 = ob[i][2], y2 = ob[i][3];
                float ai = (x2 - x1) * (y2 - y1);
                u64 bits = 0;
                int j0 = jbk * 64;
                int jmax = min(64, KK - j0);
                for (int jj = 0; jj < jmax; ++jj) {
                    float bx1 = ob[j0+jj][0], by1 = ob[j0+jj][1];
                    float bx2 = ob[j0+jj][2], by2 = ob[j0+jj][3];
                    float aj = (bx2 - bx1) * (by2 - by1);
                    float iw = fmaxf(fminf(x2, bx2) - fmaxf(x1, bx1), 0.0f);
                    float ih = fmaxf(fminf(y2, by2) - fmaxf(y1, by1), 0.0f);
                    float inter = iw * ih;
                    float iou = inter / (ai + aj - inter + 1e-9f);
                    if (iou > NMS_THR) bits |= (1ull << jj);
                }
                __hip_atomic_store(&maskT[((size_t)b * NW + jbk) * KK + i], bits,
                                   __ATOMIC_RELAXED, SC_AGENT);
            }
        }
    }
    __syncthreads();
    if (t == 0) {
        u32 tk = __hip_atomic_fetch_add(&tick[b], 1u, __ATOMIC_ACQ_REL, SC_AGENT);
        islast = (tk == (u32)(TLX - 1)) ? 1 : 0;
    }
    __syncthreads();
    if (!islast) return;

    // ---- last block: ballot fixed-point NMS (first wave), output from own LDS ----
    if (t < 64) {
        const u64* mT = maskT + (size_t)b * NW * KK;
        u64 keptW[NW];
        #pragma unroll
        for (int W = 0; W < NW; ++W) {
            int i = W * 64 + ln;
            bool inr = (i < KK);
            u64 row[NW];
            #pragma unroll
            for (int w = 0; w <= W; ++w)
                row[w] = inr ? __hip_atomic_load(&mT[(size_t)w * KK + i],
                                                 __ATOMIC_RELAXED, SC_AGENT) : 0ull;
            bool valid = inr && (tv[i] != 0);
            u64 ext = 0;
            #pragma unroll
            for (int w = 0; w < W; ++w) ext |= keptW[w] & row[w];
            bool cand = valid && (ext == 0ull);
            u64 m_self = row[W] & ((1ull << ln) - 1ull);
            u64 kept = __ballot(cand);
            while (true) {
                u64 k2 = __ballot(cand && ((kept & m_self) == 0ull));
                if (k2 == kept) break;
                kept = k2;
            }
            keptW[W] = kept;
            if (ln == 0) skept[W] = kept;
        }
    }
    __syncthreads();
    for (int kk = t; kk < KK; kk += 1024) {
        size_t o = (size_t)b * KK + kk;
        float kf = (float)((skept[kk >> 6] >> (kk & 63)) & 1ull);
        float* op = out + o * 7;
        op[0] = tb[kk][0] * kf; op[1] = tb[kk][1] * kf;
        op[2] = tb[kk][2] * kf; op[3] = tb[kk][3] * kf;
        op[4] = ts[kk] * kf;    op[5] = tc[kk] * kf;    op[6] = kf;
    }
}

extern "C" void kernel_launch(void* const* d_in, const int* in_sizes, int n_in,
                              void* d_out, int out_size, void* d_ws, size_t ws_size,
                              hipStream_t stream) {
    const float* rois   = (const float*)d_in[0];   // (B,N,4)
    const float* scores = (const float*)d_in[1];   // (B*N,C,1,1) == (B, N*C)
    const float* reg    = (const float*)d_in[2];   // (B*N,4,1,1)
    float* out = (float*)d_out;

    char* ws = (char*)d_ws;
    u32* hist1   = (u32*)(ws + WS_HIST1);
    u32* hist2   = (u32*)(ws + WS_HIST2);
    u32* gcount  = (u32*)(ws + WS_GCOUNT);
    u32* tick    = (u32*)(ws + WS_TICK);
    u32* gcount2 = (u32*)(ws + WS_GCOUNT2);
    u64* gbuf    = (u64*)(ws + WS_GBUF);
    u64* gbuf2   = (u64*)(ws + WS_GBUF2);
    u64* maskT   = (u64*)(ws + WS_MASK);

    hist1_pass<<<dim3(HB, BB), 1024, 0, stream>>>(scores, hist1, hist2, gcount);

    stage_pass<<<dim3(SGB, BB), 256, 0, stream>>>(scores, hist1, hist2, gbuf, gcount);

    refine_pass<<<dim3(D4X, BB), 1024, 0, stream>>>(
        gbuf, gcount, hist1, hist2, gbuf2, gcount2);

    tail_pass<<<dim3(TLX, BB), 1024, 0, stream>>>(
        gbuf2, gcount2, rois, reg, maskT, tick, out);
}

// Round 19
// 84.842 us; speedup vs baseline: 2.0917x; 1.4062x over previous
//
#include <hip/hip_runtime.h>
#include <stdint.h>

typedef unsigned int u32;
typedef unsigned long long u64;
typedef unsigned short u16;
typedef unsigned char u8;

#define BB 8
#define NN 8192
#define CC 80
#define KK 1000
#define NC (NN*CC)            // 655360
#define MAXIDX (NC-1)
#define NMS_THR 0.5f
#define SCORE_THR 0.05f
#define MAX_RATIO 4.135166556742356f
#define CLS_OFF 10000.0f
#define CAP 2048
#define NW 16                 // u64 words per mask row
#define HB 8                  // hist1 sub-blocks per batch (1024 thr each)
#define SGB 128               // stage blocks per batch
#define D4X 8                 // refine blocks per batch (1024 thr each)
#define NTILE 136             // lower-triangle 64x64 tiles
#define TLX 9                 // tail blocks per batch (9*16 waves >= 136 tiles)
#define LBUF 1024             // stage per-block staging buffer (u64)
#define GBUFCAP 98304         // per-batch superset capacity (u64)

#define SC_AGENT __HIP_MEMORY_SCOPE_AGENT

// ---- workspace layout (bytes) ----
#define WS_HIST1   0          // BB*HB*2048*4 = 524288 (private slices, plain stores)
#define WS_HIST2   524288     // BB*2048*4 = 65536 (atomic-accumulated; zeroed by hist1)
#define WS_CTRL    589824     // 32 u32: gcount(8), tick(8), gcount2(8), spare(8)
#define WS_GCOUNT  589824
#define WS_TICK    589856
#define WS_GCOUNT2 589888
#define WS_GBUF    589952     // 8*98304*8 = 6291456 -> 6881408
#define WS_GBUF2   6881408    // 8*2048*8 = 131072 -> 7012480
#define WS_MASK    7012480    // 8*16*1000*8 = 1024000 -> 8036480

__device__ __forceinline__ u32 mapf(float f) {
    u32 u = __float_as_uint(f);
    return (u & 0x80000000u) ? ~u : (u | 0x80000000u);
}
__device__ __forceinline__ float unmapf(u32 m) {
    u32 u = (m & 0x80000000u) ? (m ^ 0x80000000u) : ~m;
    return __uint_as_float(u);
}

// ---------------- D1: private 11-bit histograms + fold-in zeroing of control bufs -----
__global__ __launch_bounds__(1024) void hist1_pass(const float* __restrict__ scores,
                                                   u32* __restrict__ hist1,
                                                   u32* __restrict__ hist2,
                                                   u32* __restrict__ ctrl /* 32 u32 */) {
    __shared__ u32 lh[2048];
    int b = blockIdx.y, blk = blockIdx.x, t = threadIdx.x;
    for (int i = t; i < 2048; i += 1024) lh[i] = 0;
    if (t < 256) hist2[(b * HB + blk) * 256 + t] = 0u;
    else if (t < 288 && b == 0 && blk == 0) ctrl[t - 256] = 0u;
    __syncthreads();
    const float4* sp = (const float4*)(scores + (size_t)b * NC);
    int nvec = NC / 4;
    for (int v = blk * 1024 + t; v < nvec; v += HB * 1024) {
        float4 s4 = sp[v];
        float ss[4] = {s4.x, s4.y, s4.z, s4.w};
        #pragma unroll
        for (int q = 0; q < 4; ++q) {
            float s = ss[q] > SCORE_THR ? ss[q] : -1.0f;
            atomicAdd(&lh[mapf(s) >> 21], 1u);
        }
    }
    __syncthreads();
    u32* ho = hist1 + ((size_t)b * HB + blk) * 2048;
    for (int i = t; i < 2048; i += 1024) ho[i] = lh[i];
}

// ---- fast digit selects: wave shfl suffix-scan, 2 barriers total ----
__device__ __forceinline__ void sel8_fast(const u32 hv[8], u32 need,
                                          u32* wt, u32* wsuf, u32* bc) {
    int t = threadIdx.x, l = t & 63, w = t >> 6;   // 4 waves
    u32 s = 0;
    #pragma unroll
    for (int q = 0; q < 8; ++q) s += hv[q];
    u32 x = s;
    #pragma unroll
    for (int off = 1; off < 64; off <<= 1) {
        u32 y = __shfl_down(x, off);
        if (l + off < 64) x += y;
    }
    if (l == 0) wt[w] = x;
    __syncthreads();
    if (w == 0) {
        u32 v = (l < 4) ? wt[l] : 0u;
        #pragma unroll
        for (int off = 1; off < 4; off <<= 1) {
            u32 y = __shfl_down(v, off);
            if (l + off < 4) v += y;
        }
        if (l < 4) wsuf[l] = v;
    }
    __syncthreads();
    u32 sufAll = x + ((w < 3) ? wsuf[w + 1] : 0u);
    u32 cumAbove = sufAll - s;
    if (cumAbove < need && sufAll >= need) {
        u32 cum = cumAbove;
        int d = t * 8;
        #pragma unroll
        for (int q = 7; q >= 0; --q) {
            if (cum + hv[q] >= need) { d = t * 8 + q; break; }
            cum += hv[q];
        }
        bc[0] = (u32)d;
        bc[1] = need - cum;
    }
    __syncthreads();
}

__device__ __forceinline__ void sel2_fast(u32 hv0, u32 hv1, u32 need,
                                          u32* wt, u32* wsuf, u32* bc) {
    int t = threadIdx.x, l = t & 63, w = t >> 6;   // 16 waves
    u32 s = hv0 + hv1;
    u32 x = s;
    #pragma unroll
    for (int off = 1; off < 64; off <<= 1) {
        u32 y = __shfl_down(x, off);
        if (l + off < 64) x += y;
    }
    if (l == 0) wt[w] = x;
    __syncthreads();
    if (w == 0) {
        u32 v = (l < 16) ? wt[l] : 0u;
        #pragma unroll
        for (int off = 1; off < 16; off <<= 1) {
            u32 y = __shfl_down(v, off);
            if (l + off < 16) v += y;
        }
        if (l < 16) wsuf[l] = v;
    }
    __syncthreads();
    u32 sufAll = x + ((w < 15) ? wsuf[w + 1] : 0u);
    u32 cumAbove = sufAll - s;
    if (cumAbove < need && sufAll >= need) {
        if (cumAbove + hv1 >= need) { bc[0] = 2u * t + 1u; bc[1] = need - cumAbove; }
        else                        { bc[0] = 2u * t;      bc[1] = need - cumAbove - hv1; }
    }
    __syncthreads();
}

// ---------------- D2: stage d0-superset + build hist2 (bits 20..10 of d0-items) ------
__global__ __launch_bounds__(256) void stage_pass(
    const float* __restrict__ scores, const u32* __restrict__ hist1,
    u32* __restrict__ hist2, u64* __restrict__ gbuf, u32* __restrict__ gcount) {
    __shared__ u64 buf[LBUF];
    __shared__ u32 h2[2048];
    __shared__ u32 wt[4], wsuf[4];
    __shared__ u32 bc[2];
    __shared__ u32 lcnt, lbase;
    int b = blockIdx.y, bx = blockIdx.x, t = threadIdx.x;
    for (int i = t; i < 2048; i += 256) h2[i] = 0;
    if (t == 0) lcnt = 0;
    u32 hv[8];
    {
        const u32* h = hist1 + (size_t)b * HB * 2048;
        #pragma unroll
        for (int q = 0; q < 8; ++q) {
            u32 v = 0;
            #pragma unroll
            for (int sb = 0; sb < HB; ++sb) v += h[sb * 2048 + t * 8 + q];
            hv[q] = v;
        }
    }
    __syncthreads();
    sel8_fast(hv, (u32)KK, wt, wsuf, bc);
    u32 d0 = bc[0];
    const float4* sp = (const float4*)(scores + (size_t)b * NC);
    int nvec = NC / 4;
    for (int v = bx * 256 + t; v < nvec; v += SGB * 256) {
        float4 s4 = sp[v];
        float ss[4] = {s4.x, s4.y, s4.z, s4.w};
        #pragma unroll
        for (int q = 0; q < 4; ++q) {
            float s = ss[q] > SCORE_THR ? ss[q] : -1.0f;
            u32 m = mapf(s);
            u32 top = m >> 21;
            if (top >= d0) {
                u32 p = atomicAdd(&lcnt, 1u);
                if (p < LBUF) {
                    u32 idx = (u32)(v * 4 + q);
                    buf[p] = ((u64)m << 32) | (u64)(MAXIDX - idx);
                }
                if (top == d0) atomicAdd(&h2[(m >> 10) & 0x7FFu], 1u);
            }
        }
    }
    __syncthreads();
    for (int i = t; i < 2048; i += 256)
        if (h2[i]) atomicAdd(&hist2[b * 2048 + i], h2[i]);
    if (t == 0) {
        u32 c = lcnt; if (c > LBUF) c = LBUF;
        lcnt = c;
        lbase = atomicAdd(&gcount[b], c);
    }
    __syncthreads();
    u32 c = lcnt, base = lbase;
    for (u32 i = t; i < c; i += 256) {
        u32 p = base + i;
        if (p < GBUFCAP) gbuf[(size_t)b * GBUFCAP + p] = buf[i];
    }
}

// ---------------- D3: exact 22-bit filter of staged superset -> gbuf2 (compaction) ---
__global__ __launch_bounds__(1024) void refine_pass(
    const u64* __restrict__ gbuf, const u32* __restrict__ gcount,
    const u32* __restrict__ hist1, const u32* __restrict__ hist2,
    u64* __restrict__ gbuf2, u32* __restrict__ gcount2) {
    __shared__ u64 keys[CAP];
    __shared__ u32 wt[16], wsuf[16];
    __shared__ u32 bc[2];
    __shared__ u32 lcnt, lbase;
    int b = blockIdx.y, bx = blockIdx.x, t = threadIdx.x;
    if (t == 0) lcnt = 0;
    u32 hv0 = 0, hv1 = 0;
    {
        const u32* h = hist1 + (size_t)b * HB * 2048;
        #pragma unroll
        for (int sb = 0; sb < HB; ++sb) {
            hv0 += h[sb * 2048 + 2 * t];
            hv1 += h[sb * 2048 + 2 * t + 1];
        }
    }
    __syncthreads();
    sel2_fast(hv0, hv1, (u32)KK, wt, wsuf, bc);
    u32 d0 = bc[0], rem = bc[1];
    __syncthreads();
    sel2_fast(hist2[b * 2048 + 2 * t], hist2[b * 2048 + 2 * t + 1], rem, wt, wsuf, bc);
    u32 thr = ((d0 << 11) | bc[0]) << 10;

    u32 cnt = gcount[b]; if (cnt > GBUFCAP) cnt = GBUFCAP;
    const u64* gb = gbuf + (size_t)b * GBUFCAP;
    u32 chunk = (cnt + D4X - 1) / D4X;
    u32 lo = bx * chunk, hi = lo + chunk; if (hi > cnt) hi = cnt;
    for (u32 i = lo + t; i < hi; i += 1024) {
        u64 key = gb[i];
        if ((u32)(key >> 32) >= thr) {
            u32 p = atomicAdd(&lcnt, 1u);
            if (p < CAP) keys[p] = key;
        }
    }
    __syncthreads();
    if (t == 0) {
        u32 c = lcnt; if (c > CAP) c = CAP;
        lcnt = c;
        lbase = atomicAdd(&gcount2[b], c);      // default atomicAdd = device scope
    }
    __syncthreads();
    u32 c = lcnt, base = lbase;
    for (u32 i = t; i < c; i += 1024) {
        u32 p = base + i;
        if (p < CAP) gbuf2[(size_t)b * CAP + p] = keys[i];   // plain stores
    }
}

// decode one key into the LDS tables at row r
__device__ __forceinline__ void decode_lds(
    int b, u32 r, u64 key,
    const float* __restrict__ rois, const float* __restrict__ reg,
    float (*tb)[4], float (*ob)[4], float* ts, float* tc, u8* tv) {
    u32 m = (u32)(key >> 32);
    u32 idx = (u32)MAXIDX - (u32)(key & 0xFFFFFFFFu);
    float score = unmapf(m);
    u8 vld = (score > SCORE_THR) ? 1 : 0;
    int n = idx / CC, c = idx % CC;
    float cf = (float)(c + 1);
    const float* rr = rois + ((size_t)b * NN + n) * 4;
    const float* d  = reg  + ((size_t)b * NN + n) * 4;
    float x1 = rr[0], y1 = rr[1], x2 = rr[2], y2 = rr[3];
    float w = x2 - x1, h = y2 - y1;
    float cx = x1 + 0.5f * w, cy = y1 + 0.5f * h;
    float dx = d[0], dy = d[1];
    float dw = fminf(fmaxf(d[2], -MAX_RATIO), MAX_RATIO);
    float dh = fminf(fmaxf(d[3], -MAX_RATIO), MAX_RATIO);
    float pw = w * expf(dw), ph = h * expf(dh);
    float pcx = cx + dx * w, pcy = cy + dy * h;
    float box0 = pcx - 0.5f * pw, box1 = pcy - 0.5f * ph;
    float box2 = pcx + 0.5f * pw, box3 = pcy + 0.5f * ph;
    tb[r][0] = box0; tb[r][1] = box1; tb[r][2] = box2; tb[r][3] = box3;
    ts[r] = score; tc[r] = cf; tv[r] = vld;
    float off = cf * CLS_OFF;
    ob[r][0] = box0 + off; ob[r][1] = box1 + off;
    ob[r][2] = box2 + off; ob[r][3] = box3 + off;
}

// ---------------- D4: fused tail — counting-sort rank + decode + IoU + NMS + output --
__global__ __launch_bounds__(1024) void tail_pass(
    const u64* __restrict__ gbuf2, const u32* __restrict__ gcount2,
    const float* __restrict__ rois, const float* __restrict__ reg,
    u64* __restrict__ maskT, u32* __restrict__ tick, float* __restrict__ out) {
    __shared__ u64 keys[CAP];      // 16 KB
    __shared__ u64 skeys[CAP];     // 16 KB bin-ordered
    __shared__ u32 cntb[2048];     // 8 KB
    __shared__ u32 bbase[2048];    // 8 KB
    __shared__ u32 offb[2048];     // 8 KB
    __shared__ float tb[KK][4];    // 16 KB
    __shared__ float ob[KK][4];    // 16 KB
    __shared__ float ts[KK];       // 4 KB
    __shared__ float tc[KK];       // 4 KB
    __shared__ u8  tv[KK];         // 1 KB
    __shared__ u64 skept[NW];
    __shared__ u32 wt[16], wsuf[16];
    __shared__ u32 redmin[16], redmax[16];
    __shared__ u32 smin_s, smax_s;
    __shared__ int islast;
    int b = blockIdx.y, bx = blockIdx.x, t = threadIdx.x;
    int wv = t >> 6, ln = t & 63;  // 16 waves

    // ---- load compacted candidates + m-range reduce; zero bin arrays ----
    u32 cnt2 = gcount2[b]; if (cnt2 > CAP) cnt2 = CAP;
    cntb[2 * t] = 0; cntb[2 * t + 1] = 0;
    u32 mymax = 0u, mymin = 0xFFFFFFFFu;
    for (u32 i = t; i < cnt2; i += 1024) {
        u64 key = gbuf2[(size_t)b * CAP + i];
        keys[i] = key;
        u32 m = (u32)(key >> 32);
        if (m > mymax) mymax = m;
        if (m < mymin) mymin = m;
    }
    #pragma unroll
    for (int off = 32; off >= 1; off >>= 1) {
        u32 ymx = __shfl_down(mymax, off);
        u32 ymn = __shfl_down(mymin, off);
        if (ymx > mymax) mymax = ymx;
        if (ymn < mymin) mymin = ymn;
    }
    if (ln == 0) { redmax[wv] = mymax; redmin[wv] = mymin; }
    __syncthreads();
    if (t == 0) {
        u32 mx = 0u, mn = 0xFFFFFFFFu;
        #pragma unroll
        for (int i = 0; i < 16; ++i) {
            if (redmax[i] > mx) mx = redmax[i];
            if (redmin[i] < mn) mn = redmin[i];
        }
        smax_s = mx; smin_s = mn;
    }
    __syncthreads();
    u32 smin = smin_s;
    u32 range = smax_s - smin;
    u32 SH = (range >= 2048u) ? (32u - (u32)__clz((int)range) - 11u) : 0u;

    // ---- bin histogram (one atomic per key) ----
    for (u32 i = t; i < cnt2; i += 1024) {
        u32 m = (u32)(keys[i] >> 32);
        atomicAdd(&cntb[(m - smin) >> SH], 1u);
    }
    __syncthreads();

    // ---- suffix-scan -> bbase[bin] = #keys in strictly higher bins; zero offb ----
    {
        u32 c0b = cntb[2 * t], c1b = cntb[2 * t + 1];
        u32 s = c0b + c1b;
        u32 x = s;
        #pragma unroll
        for (int off = 1; off < 64; off <<= 1) {
            u32 y = __shfl_down(x, off);
            if (ln + off < 64) x += y;
        }
        if (ln == 0) wt[wv] = x;
        __syncthreads();
        if (wv == 0) {
            u32 v = (ln < 16) ? wt[ln] : 0u;
            #pragma unroll
            for (int off = 1; off < 16; off <<= 1) {
                u32 y = __shfl_down(v, off);
                if (ln + off < 16) v += y;
            }
            if (ln < 16) wsuf[ln] = v;
        }
        __syncthreads();
        u32 sufAll = x + ((wv < 15) ? wsuf[wv + 1] : 0u);
        bbase[2 * t]     = sufAll - c0b;   // bins above 2t (incl. 2t+1)
        bbase[2 * t + 1] = sufAll - s;     // bins above 2t+1
        offb[2 * t] = 0; offb[2 * t + 1] = 0;
    }
    __syncthreads();

    // ---- scatter into bin-ordered skeys ----
    for (u32 i = t; i < cnt2; i += 1024) {
        u64 key = keys[i];
        u32 bin = ((u32)(key >> 32) - smin) >> SH;
        u32 p = bbase[bin] + atomicAdd(&offb[bin], 1u);
        skeys[p] = key;
    }
    __syncthreads();

    // ---- exact rank = bbase[bin] + intra-bin greater-count; decode immediately ----
    for (u32 p = t; p < cnt2; p += 1024) {
        u64 key = skeys[p];
        u32 bin = ((u32)(key >> 32) - smin) >> SH;
        u32 lo = bbase[bin], hi = lo + cntb[bin];
        u32 r = lo;
        for (u32 q = lo; q < hi; ++q)
            r += (skeys[q] > key) ? 1u : 0u;
        if (r < KK) decode_lds(b, r, key, rois, reg, tb, ob, ts, tc, tv);
    }
    // filler rows [cnt2, KK)
    for (u32 r = cnt2 + t; r < KK; r += 1024) {
        ts[r] = -1.0f; tc[r] = 0.0f; tv[r] = 0;
        tb[r][0] = 0; tb[r][1] = 0; tb[r][2] = 0; tb[r][3] = 0;
        ob[r][0] = 0; ob[r][1] = 0; ob[r][2] = 0; ob[r][3] = 0;
    }
    __syncthreads();

    // ---- IoU: one 64x64 lower-triangle tile per wave; T = bx*16 + wv ----
    {
        int T = bx * 16 + wv;
        if (T < NTILE) {
            int ib = (int)((sqrtf(8.0f * (float)T + 1.0f) - 1.0f) * 0.5f);
            while ((ib + 1) * (ib + 2) / 2 <= T) ++ib;
            while (ib * (ib + 1) / 2 > T) --ib;
            int jbk = T - ib * (ib + 1) / 2;
            int i = ib * 64 + ln;
            if (i < KK) {
                float x1 = ob[i][0], y1 = ob[i][1], x2 = ob[i][2], y2 = ob[i][3];
                float ai = (x2 - x1) * (y2 - y1);
                u64 bits = 0;
                int j0 = jbk * 64;
                int jmax = min(64, KK - j0);
                for (int jj = 0; jj < jmax; ++jj) {
                    float bx1 = ob[j0+jj][0], by1 = ob[j0+jj][1];
                    float bx2 = ob[j0+jj][2], by2 = ob[j0+jj][3];
                    float aj = (bx2 - bx1) * (by2 - by1);
                    float iw = fmaxf(fminf(x2, bx2) - fmaxf(x1, bx1), 0.0f);
                    float ih = fmaxf(fminf(y2, by2) - fmaxf(y1, by1), 0.0f);
                    float inter = iw * ih;
                    float iou = inter / (ai + aj - inter + 1e-9f);
                    if (iou > NMS_THR) bits |= (1ull << jj);
                }
                __hip_atomic_store(&maskT[((size_t)b * NW + jbk) * KK + i], bits,
                                   __ATOMIC_RELAXED, SC_AGENT);
            }
        }
    }
    __syncthreads();
    if (t == 0) {
        u32 tk = __hip_atomic_fetch_add(&tick[b], 1u, __ATOMIC_ACQ_REL, SC_AGENT);
        islast = (tk == (u32)(TLX - 1)) ? 1 : 0;
    }
    __syncthreads();
    if (!islast) return;

    // ---- last block: ballot fixed-point NMS (first wave), output from own LDS ----
    if (t < 64) {
        const u64* mT = maskT + (size_t)b * NW * KK;
        u64 keptW[NW];
        #pragma unroll
        for (int W = 0; W < NW; ++W) {
            int i = W * 64 + ln;
            bool inr = (i < KK);
            u64 row[NW];
            #pragma unroll
            for (int w = 0; w <= W; ++w)
                row[w] = inr ? __hip_atomic_load(&mT[(size_t)w * KK + i],
                                                 __ATOMIC_RELAXED, SC_AGENT) : 0ull;
            bool valid = inr && (tv[i] != 0);
            u64 ext = 0;
            #pragma unroll
            for (int w = 0; w < W; ++w) ext |= keptW[w] & row[w];
            bool cand = valid && (ext == 0ull);
            u64 m_self = row[W] & ((1ull << ln) - 1ull);
            u64 kept = __ballot(cand);
            while (true) {
                u64 k2 = __ballot(cand && ((kept & m_self) == 0ull));
                if (k2 == kept) break;
                kept = k2;
            }
            keptW[W] = kept;
            if (ln == 0) skept[W] = kept;
        }
    }
    __syncthreads();
    for (int kk = t; kk < KK; kk += 1024) {
        size_t o = (size_t)b * KK + kk;
        float kf = (float)((skept[kk >> 6] >> (kk & 63)) & 1ull);
        float* op = out + o * 7;
        op[0] = tb[kk][0] * kf; op[1] = tb[kk][1] * kf;
        op[2] = tb[kk][2] * kf; op[3] = tb[kk][3] * kf;
        op[4] = ts[kk] * kf;    op[5] = tc[kk] * kf;    op[6] = kf;
    }
}

extern "C" void kernel_launch(void* const* d_in, const int* in_sizes, int n_in,
                              void* d_out, int out_size, void* d_ws, size_t ws_size,
                              hipStream_t stream) {
    const float* rois   = (const float*)d_in[0];   // (B,N,4)
    const float* scores = (const float*)d_in[1];   // (B*N,C,1,1) == (B, N*C)
    const float* reg    = (const float*)d_in[2];   // (B*N,4,1,1)
    float* out = (float*)d_out;

    char* ws = (char*)d_ws;
    u32* hist1   = (u32*)(ws + WS_HIST1);
    u32* hist2   = (u32*)(ws + WS_HIST2);
    u32* gcount  = (u32*)(ws + WS_GCOUNT);
    u32* tick    = (u32*)(ws + WS_TICK);
    u32* gcount2 = (u32*)(ws + WS_GCOUNT2);
    u64* gbuf    = (u64*)(ws + WS_GBUF);
    u64* gbuf2   = (u64*)(ws + WS_GBUF2);
    u64* maskT   = (u64*)(ws + WS_MASK);

    hist1_pass<<<dim3(HB, BB), 1024, 0, stream>>>(scores, hist1, hist2, gcount);

    stage_pass<<<dim3(SGB, BB), 256, 0, stream>>>(scores, hist1, hist2, gbuf, gcount);

    refine_pass<<<dim3(D4X, BB), 1024, 0, stream>>>(
        gbuf, gcount, hist1, hist2, gbuf2, gcount2);

    tail_pass<<<dim3(TLX, BB), 1024, 0, stream>>>(
        gbuf2, gcount2, rois, reg, maskT, tick, out);
}

// Round 20
// 83.957 us; speedup vs baseline: 2.1138x; 1.0105x over previous
//
#include <hip/hip_runtime.h>
#include <stdint.h>

typedef unsigned int u32;
typedef unsigned long long u64;
typedef unsigned short u16;
typedef unsigned char u8;

#define BB 8
#define NN 8192
#define CC 80
#define KK 1000
#define NC (NN*CC)            // 655360
#define MAXIDX (NC-1)
#define NMS_THR 0.5f
#define SCORE_THR 0.05f
#define MAX_RATIO 4.135166556742356f
#define CLS_OFF 10000.0f
#define CAP 2048
#define NW 16                 // u64 words per mask row
#define HB 8                  // hist1 sub-blocks per batch (1024 thr each)
#define SGB 128               // stage blocks per batch
#define D4X 8                 // refine blocks per batch (1024 thr each)
#define NTILE 136             // lower-triangle 64x64 tiles
#define TLX 9                 // tail blocks per batch (9*16 waves >= 136 tiles)
#define LBUF 1024             // stage per-block staging buffer (u64)
#define GBUFCAP 98304         // per-batch superset capacity (u64)

#define SC_AGENT __HIP_MEMORY_SCOPE_AGENT

// ---- workspace layout (bytes) ----
#define WS_HIST1   0          // BB*HB*2048*4 = 524288 (private slices, plain stores)
#define WS_HIST2   524288     // BB*2048*4 = 65536 (atomic-accumulated; zeroed by hist1)
#define WS_CTRL    589824     // 32 u32: gcount(8), tick(8), gcount2(8), spare(8)
#define WS_GCOUNT  589824
#define WS_TICK    589856
#define WS_GCOUNT2 589888
#define WS_GBUF    589952     // 8*98304*8 = 6291456 -> 6881408
#define WS_GBUF2   6881408    // 8*2048*8 = 131072 -> 7012480
#define WS_BBOX    7012480    // 8*2048*16 = 262144 -> 7274624
#define WS_MASK    7274624    // 8*16*1000*8 = 1024000 -> 8298624

__device__ __forceinline__ u32 mapf(float f) {
    u32 u = __float_as_uint(f);
    return (u & 0x80000000u) ? ~u : (u | 0x80000000u);
}
__device__ __forceinline__ float unmapf(u32 m) {
    u32 u = (m & 0x80000000u) ? (m ^ 0x80000000u) : ~m;
    return __uint_as_float(u);
}

// ---------------- D1: private 11-bit histograms + fold-in zeroing of control bufs -----
__global__ __launch_bounds__(1024) void hist1_pass(const float* __restrict__ scores,
                                                   u32* __restrict__ hist1,
                                                   u32* __restrict__ hist2,
                                                   u32* __restrict__ ctrl /* 32 u32 */) {
    __shared__ u32 lh[2048];
    int b = blockIdx.y, blk = blockIdx.x, t = threadIdx.x;
    for (int i = t; i < 2048; i += 1024) lh[i] = 0;
    if (t < 256) hist2[(b * HB + blk) * 256 + t] = 0u;
    else if (t < 288 && b == 0 && blk == 0) ctrl[t - 256] = 0u;
    __syncthreads();
    const float4* sp = (const float4*)(scores + (size_t)b * NC);
    int nvec = NC / 4;
    for (int v = blk * 1024 + t; v < nvec; v += HB * 1024) {
        float4 s4 = sp[v];
        float ss[4] = {s4.x, s4.y, s4.z, s4.w};
        #pragma unroll
        for (int q = 0; q < 4; ++q) {
            float s = ss[q] > SCORE_THR ? ss[q] : -1.0f;
            atomicAdd(&lh[mapf(s) >> 21], 1u);
        }
    }
    __syncthreads();
    u32* ho = hist1 + ((size_t)b * HB + blk) * 2048;
    for (int i = t; i < 2048; i += 1024) ho[i] = lh[i];
}

// ---- fast digit selects: wave shfl suffix-scan, 2 barriers total ----
__device__ __forceinline__ void sel8_fast(const u32 hv[8], u32 need,
                                          u32* wt, u32* wsuf, u32* bc) {
    int t = threadIdx.x, l = t & 63, w = t >> 6;   // 4 waves
    u32 s = 0;
    #pragma unroll
    for (int q = 0; q < 8; ++q) s += hv[q];
    u32 x = s;
    #pragma unroll
    for (int off = 1; off < 64; off <<= 1) {
        u32 y = __shfl_down(x, off);
        if (l + off < 64) x += y;
    }
    if (l == 0) wt[w] = x;
    __syncthreads();
    if (w == 0) {
        u32 v = (l < 4) ? wt[l] : 0u;
        #pragma unroll
        for (int off = 1; off < 4; off <<= 1) {
            u32 y = __shfl_down(v, off);
            if (l + off < 4) v += y;
        }
        if (l < 4) wsuf[l] = v;
    }
    __syncthreads();
    u32 sufAll = x + ((w < 3) ? wsuf[w + 1] : 0u);
    u32 cumAbove = sufAll - s;
    if (cumAbove < need && sufAll >= need) {
        u32 cum = cumAbove;
        int d = t * 8;
        #pragma unroll
        for (int q = 7; q >= 0; --q) {
            if (cum + hv[q] >= need) { d = t * 8 + q; break; }
            cum += hv[q];
        }
        bc[0] = (u32)d;
        bc[1] = need - cum;
    }
    __syncthreads();
}

__device__ __forceinline__ void sel2_fast(u32 hv0, u32 hv1, u32 need,
                                          u32* wt, u32* wsuf, u32* bc) {
    int t = threadIdx.x, l = t & 63, w = t >> 6;   // 16 waves
    u32 s = hv0 + hv1;
    u32 x = s;
    #pragma unroll
    for (int off = 1; off < 64; off <<= 1) {
        u32 y = __shfl_down(x, off);
        if (l + off < 64) x += y;
    }
    if (l == 0) wt[w] = x;
    __syncthreads();
    if (w == 0) {
        u32 v = (l < 16) ? wt[l] : 0u;
        #pragma unroll
        for (int off = 1; off < 16; off <<= 1) {
            u32 y = __shfl_down(v, off);
            if (l + off < 16) v += y;
        }
        if (l < 16) wsuf[l] = v;
    }
    __syncthreads();
    u32 sufAll = x + ((w < 15) ? wsuf[w + 1] : 0u);
    u32 cumAbove = sufAll - s;
    if (cumAbove < need && sufAll >= need) {
        if (cumAbove + hv1 >= need) { bc[0] = 2u * t + 1u; bc[1] = need - cumAbove; }
        else                        { bc[0] = 2u * t;      bc[1] = need - cumAbove - hv1; }
    }
    __syncthreads();
}

// ---------------- D2: stage d0-superset + build hist2 (bits 20..10 of d0-items) ------
__global__ __launch_bounds__(256) void stage_pass(
    const float* __restrict__ scores, const u32* __restrict__ hist1,
    u32* __restrict__ hist2, u64* __restrict__ gbuf, u32* __restrict__ gcount) {
    __shared__ u64 buf[LBUF];
    __shared__ u32 h2[2048];
    __shared__ u32 wt[4], wsuf[4];
    __shared__ u32 bc[2];
    __shared__ u32 lcnt, lbase;
    int b = blockIdx.y, bx = blockIdx.x, t = threadIdx.x;
    for (int i = t; i < 2048; i += 256) h2[i] = 0;
    if (t == 0) lcnt = 0;
    u32 hv[8];
    {
        const u32* h = hist1 + (size_t)b * HB * 2048;
        #pragma unroll
        for (int q = 0; q < 8; ++q) {
            u32 v = 0;
            #pragma unroll
            for (int sb = 0; sb < HB; ++sb) v += h[sb * 2048 + t * 8 + q];
            hv[q] = v;
        }
    }
    __syncthreads();
    sel8_fast(hv, (u32)KK, wt, wsuf, bc);
    u32 d0 = bc[0];
    const float4* sp = (const float4*)(scores + (size_t)b * NC);
    int nvec = NC / 4;
    for (int v = bx * 256 + t; v < nvec; v += SGB * 256) {
        float4 s4 = sp[v];
        float ss[4] = {s4.x, s4.y, s4.z, s4.w};
        #pragma unroll
        for (int q = 0; q < 4; ++q) {
            float s = ss[q] > SCORE_THR ? ss[q] : -1.0f;
            u32 m = mapf(s);
            u32 top = m >> 21;
            if (top >= d0) {
                u32 p = atomicAdd(&lcnt, 1u);
                if (p < LBUF) {
                    u32 idx = (u32)(v * 4 + q);
                    buf[p] = ((u64)m << 32) | (u64)(MAXIDX - idx);
                }
                if (top == d0) atomicAdd(&h2[(m >> 10) & 0x7FFu], 1u);
            }
        }
    }
    __syncthreads();
    for (int i = t; i < 2048; i += 256)
        if (h2[i]) atomicAdd(&hist2[b * 2048 + i], h2[i]);
    if (t == 0) {
        u32 c = lcnt; if (c > LBUF) c = LBUF;
        lcnt = c;
        lbase = atomicAdd(&gcount[b], c);
    }
    __syncthreads();
    u32 c = lcnt, base = lbase;
    for (u32 i = t; i < c; i += 256) {
        u32 p = base + i;
        if (p < GBUFCAP) gbuf[(size_t)b * GBUFCAP + p] = buf[i];
    }
}

// ---------------- D3: exact 22-bit filter -> gbuf2 + ONE-TIME box decode -> bbox -----
__global__ __launch_bounds__(1024) void refine_pass(
    const u64* __restrict__ gbuf, const u32* __restrict__ gcount,
    const u32* __restrict__ hist1, const u32* __restrict__ hist2,
    const float* __restrict__ rois, const float* __restrict__ reg,
    u64* __restrict__ gbuf2, float4* __restrict__ bbox, u32* __restrict__ gcount2) {
    __shared__ u64 keys[CAP];
    __shared__ u32 wt[16], wsuf[16];
    __shared__ u32 bc[2];
    __shared__ u32 lcnt, lbase;
    int b = blockIdx.y, bx = blockIdx.x, t = threadIdx.x;
    if (t == 0) lcnt = 0;
    u32 hv0 = 0, hv1 = 0;
    {
        const u32* h = hist1 + (size_t)b * HB * 2048;
        #pragma unroll
        for (int sb = 0; sb < HB; ++sb) {
            hv0 += h[sb * 2048 + 2 * t];
            hv1 += h[sb * 2048 + 2 * t + 1];
        }
    }
    __syncthreads();
    sel2_fast(hv0, hv1, (u32)KK, wt, wsuf, bc);
    u32 d0 = bc[0], rem = bc[1];
    __syncthreads();
    sel2_fast(hist2[b * 2048 + 2 * t], hist2[b * 2048 + 2 * t + 1], rem, wt, wsuf, bc);
    u32 thr = ((d0 << 11) | bc[0]) << 10;

    u32 cnt = gcount[b]; if (cnt > GBUFCAP) cnt = GBUFCAP;
    const u64* gb = gbuf + (size_t)b * GBUFCAP;
    u32 chunk = (cnt + D4X - 1) / D4X;
    u32 lo = bx * chunk, hi = lo + chunk; if (hi > cnt) hi = cnt;
    for (u32 i = lo + t; i < hi; i += 1024) {
        u64 key = gb[i];
        if ((u32)(key >> 32) >= thr) {
            u32 p = atomicAdd(&lcnt, 1u);
            if (p < CAP) keys[p] = key;
        }
    }
    __syncthreads();
    if (t == 0) {
        u32 c = lcnt; if (c > CAP) c = CAP;
        lcnt = c;
        lbase = atomicAdd(&gcount2[b], c);      // default atomicAdd = device scope
    }
    __syncthreads();
    u32 c = lcnt, base = lbase;
    for (u32 i = t; i < c; i += 1024) {
        u32 p = base + i;
        if (p < CAP) {
            u64 key = keys[i];
            gbuf2[(size_t)b * CAP + p] = key;
            // one-time decode: box depends only on key + rois/reg
            u32 idx = (u32)MAXIDX - (u32)(key & 0xFFFFFFFFu);
            int n = idx / CC;
            const float* rr = rois + ((size_t)b * NN + n) * 4;
            const float* d  = reg  + ((size_t)b * NN + n) * 4;
            float x1 = rr[0], y1 = rr[1], x2 = rr[2], y2 = rr[3];
            float w = x2 - x1, h = y2 - y1;
            float cx = x1 + 0.5f * w, cy = y1 + 0.5f * h;
            float dx = d[0], dy = d[1];
            float dw = fminf(fmaxf(d[2], -MAX_RATIO), MAX_RATIO);
            float dh = fminf(fmaxf(d[3], -MAX_RATIO), MAX_RATIO);
            float pw = w * expf(dw), ph = h * expf(dh);
            float pcx = cx + dx * w, pcy = cy + dy * h;
            bbox[(size_t)b * CAP + p] = make_float4(
                pcx - 0.5f * pw, pcy - 0.5f * ph, pcx + 0.5f * pw, pcy + 0.5f * ph);
        }
    }
}

// ---------------- D4: fused tail — counting-sort rank + tables + IoU + NMS + output --
__global__ __launch_bounds__(1024) void tail_pass(
    const u64* __restrict__ gbuf2, const float4* __restrict__ bboxg,
    const u32* __restrict__ gcount2,
    u64* __restrict__ maskT, u32* __restrict__ tick, float* __restrict__ out) {
    __shared__ u64 keys[CAP];      // 16 KB
    __shared__ u64 skeys[CAP];     // 16 KB bin-ordered
    __shared__ u32 cntb[2048];     // 8 KB
    __shared__ u32 bbase[2048];    // 8 KB
    __shared__ u32 offb[2048];     // 8 KB
    __shared__ float tb[KK][4];    // 16 KB
    __shared__ float ob[KK][4];    // 16 KB
    __shared__ float ts[KK];       // 4 KB
    __shared__ float tc[KK];       // 4 KB
    __shared__ u8  tv[KK];         // 1 KB
    __shared__ u64 skept[NW];
    __shared__ u32 wt[16], wsuf[16];
    __shared__ u32 redmin[16], redmax[16];
    __shared__ u32 smin_s, smax_s;
    __shared__ int islast;
    int b = blockIdx.y, bx = blockIdx.x, t = threadIdx.x;
    int wv = t >> 6, ln = t & 63;  // 16 waves

    // ---- load compacted candidates + m-range reduce; zero bin arrays ----
    u32 cnt2 = gcount2[b]; if (cnt2 > CAP) cnt2 = CAP;
    cntb[2 * t] = 0; cntb[2 * t + 1] = 0;
    u32 mymax = 0u, mymin = 0xFFFFFFFFu;
    for (u32 i = t; i < cnt2; i += 1024) {
        u64 key = gbuf2[(size_t)b * CAP + i];
        keys[i] = key;
        u32 m = (u32)(key >> 32);
        if (m > mymax) mymax = m;
        if (m < mymin) mymin = m;
    }
    #pragma unroll
    for (int off = 32; off >= 1; off >>= 1) {
        u32 ymx = __shfl_down(mymax, off);
        u32 ymn = __shfl_down(mymin, off);
        if (ymx > mymax) mymax = ymx;
        if (ymn < mymin) mymin = ymn;
    }
    if (ln == 0) { redmax[wv] = mymax; redmin[wv] = mymin; }
    __syncthreads();
    if (t == 0) {
        u32 mx = 0u, mn = 0xFFFFFFFFu;
        #pragma unroll
        for (int i = 0; i < 16; ++i) {
            if (redmax[i] > mx) mx = redmax[i];
            if (redmin[i] < mn) mn = redmin[i];
        }
        smax_s = mx; smin_s = mn;
    }
    __syncthreads();
    u32 smin = smin_s;
    u32 range = smax_s - smin;
    u32 SH = (range >= 2048u) ? (32u - (u32)__clz((int)range) - 11u) : 0u;

    // ---- bin histogram (one atomic per key) ----
    for (u32 i = t; i < cnt2; i += 1024) {
        u32 m = (u32)(keys[i] >> 32);
        atomicAdd(&cntb[(m - smin) >> SH], 1u);
    }
    __syncthreads();

    // ---- suffix-scan -> bbase[bin] = #keys in strictly higher bins; zero offb ----
    {
        u32 c0b = cntb[2 * t], c1b = cntb[2 * t + 1];
        u32 s = c0b + c1b;
        u32 x = s;
        #pragma unroll
        for (int off = 1; off < 64; off <<= 1) {
            u32 y = __shfl_down(x, off);
            if (ln + off < 64) x += y;
        }
        if (ln == 0) wt[wv] = x;
        __syncthreads();
        if (wv == 0) {
            u32 v = (ln < 16) ? wt[ln] : 0u;
            #pragma unroll
            for (int off = 1; off < 16; off <<= 1) {
                u32 y = __shfl_down(v, off);
                if (ln + off < 16) v += y;
            }
            if (ln < 16) wsuf[ln] = v;
        }
        __syncthreads();
        u32 sufAll = x + ((wv < 15) ? wsuf[wv + 1] : 0u);
        bbase[2 * t]     = sufAll - c0b;
        bbase[2 * t + 1] = sufAll - s;
        offb[2 * t] = 0; offb[2 * t + 1] = 0;
    }
    __syncthreads();

    // ---- scatter into bin-ordered skeys ----
    for (u32 i = t; i < cnt2; i += 1024) {
        u64 key = keys[i];
        u32 bin = ((u32)(key >> 32) - smin) >> SH;
        u32 p = bbase[bin] + atomicAdd(&offb[bin], 1u);
        skeys[p] = key;
    }
    __syncthreads();

    // ---- rank (iterating original index i -> bbox[i] stays linear) + fill tables ----
    for (u32 i = t; i < cnt2; i += 1024) {
        u64 key = keys[i];
        u32 bin = ((u32)(key >> 32) - smin) >> SH;
        u32 lo = bbase[bin], hi = lo + cntb[bin];
        u32 r = lo;
        for (u32 q = lo; q < hi; ++q)
            r += (skeys[q] > key) ? 1u : 0u;
        if (r < KK) {
            float4 bx = bboxg[(size_t)b * CAP + i];
            u32 m = (u32)(key >> 32);
            u32 idx = (u32)MAXIDX - (u32)(key & 0xFFFFFFFFu);
            float score = unmapf(m);
            float cf = (float)((int)(idx % CC) + 1);
            tb[r][0] = bx.x; tb[r][1] = bx.y; tb[r][2] = bx.z; tb[r][3] = bx.w;
            ts[r] = score; tc[r] = cf; tv[r] = (score > SCORE_THR) ? 1 : 0;
            float off = cf * CLS_OFF;
            ob[r][0] = bx.x + off; ob[r][1] = bx.y + off;
            ob[r][2] = bx.z + off; ob[r][3] = bx.w + off;
        }
    }
    // filler rows [cnt2, KK)
    for (u32 r = cnt2 + t; r < KK; r += 1024) {
        ts[r] = -1.0f; tc[r] = 0.0f; tv[r] = 0;
        tb[r][0] = 0; tb[r][1] = 0; tb[r][2] = 0; tb[r][3] = 0;
        ob[r][0] = 0; ob[r][1] = 0; ob[r][2] = 0; ob[r][3] = 0;
    }
    __syncthreads();

    // ---- IoU: one 64x64 lower-triangle tile per wave; T = bx*16 + wv ----
    {
        int T = bx * 16 + wv;
        if (T < NTILE) {
            int ib = (int)((sqrtf(8.0f * (float)T + 1.0f) - 1.0f) * 0.5f);
            while ((ib + 1) * (ib + 2) / 2 <= T) ++ib;
            while (ib * (ib + 1) / 2 > T) --ib;
            int jbk = T - ib * (ib + 1) / 2;
            int i = ib * 64 + ln;
            if (i < KK) {
                float x1 = ob[i][0], y1 = ob[i][1], x2 = ob[i][2], y2 = ob[i][3];
                float ai = (x2 - x1) * (y2 - y1);
                u64 bits = 0;
                int j0 = jbk * 64;
                int jmax = min(64, KK - j0);
                for (int jj = 0; jj < jmax; ++jj) {
                    float bx1 = ob[j0+jj][0], by1 = ob[j0+jj][1];
                    float bx2 = ob[j0+jj][2], by2 = ob[j0+jj][3];
                    float aj = (bx2 - bx1) * (by2 - by1);
                    float iw = fmaxf(fminf(x2, bx2) - fmaxf(x1, bx1), 0.0f);
                    float ih = fmaxf(fminf(y2, by2) - fmaxf(y1, by1), 0.0f);
                    float inter = iw * ih;
                    float iou = inter / (ai + aj - inter + 1e-9f);
                    if (iou > NMS_THR) bits |= (1ull << jj);
                }
                __hip_atomic_store(&maskT[((size_t)b * NW + jbk) * KK + i], bits,
                                   __ATOMIC_RELAXED, SC_AGENT);
            }
        }
    }
    __syncthreads();
    if (t == 0) {
        u32 tk = __hip_atomic_fetch_add(&tick[b], 1u, __ATOMIC_ACQ_REL, SC_AGENT);
        islast = (tk == (u32)(TLX - 1)) ? 1 : 0;
    }
    __syncthreads();
    if (!islast) return;

    // ---- last block: ballot fixed-point NMS (first wave), output from own LDS ----
    if (t < 64) {
        const u64* mT = maskT + (size_t)b * NW * KK;
        u64 keptW[NW];
        #pragma unroll
        for (int W = 0; W < NW; ++W) {
            int i = W * 64 + ln;
            bool inr = (i < KK);
            u64 row[NW];
            #pragma unroll
            for (int w = 0; w <= W; ++w)
                row[w] = inr ? __hip_atomic_load(&mT[(size_t)w * KK + i],
                                                 __ATOMIC_RELAXED, SC_AGENT) : 0ull;
            bool valid = inr && (tv[i] != 0);
            u64 ext = 0;
            #pragma unroll
            for (int w = 0; w < W; ++w) ext |= keptW[w] & row[w];
            bool cand = valid && (ext == 0ull);
            u64 m_self = row[W] & ((1ull << ln) - 1ull);
            u64 kept = __ballot(cand);
            while (true) {
                u64 k2 = __ballot(cand && ((kept & m_self) == 0ull));
                if (k2 == kept) break;
                kept = k2;
            }
            keptW[W] = kept;
            if (ln == 0) skept[W] = kept;
        }
    }
    __syncthreads();
    for (int kk = t; kk < KK; kk += 1024) {
        size_t o = (size_t)b * KK + kk;
        float kf = (float)((skept[kk >> 6] >> (kk & 63)) & 1ull);
        float* op = out + o * 7;
        op[0] = tb[kk][0] * kf; op[1] = tb[kk][1] * kf;
        op[2] = tb[kk][2] * kf; op[3] = tb[kk][3] * kf;
        op[4] = ts[kk] * kf;    op[5] = tc[kk] * kf;    op[6] = kf;
    }
}

extern "C" void kernel_launch(void* const* d_in, const int* in_sizes, int n_in,
                              void* d_out, int out_size, void* d_ws, size_t ws_size,
                              hipStream_t stream) {
    const float* rois   = (const float*)d_in[0];   // (B,N,4)
    const float* scores = (const float*)d_in[1];   // (B*N,C,1,1) == (B, N*C)
    const float* reg    = (const float*)d_in[2];   // (B*N,4,1,1)
    float* out = (float*)d_out;

    char* ws = (char*)d_ws;
    u32* hist1   = (u32*)(ws + WS_HIST1);
    u32* hist2   = (u32*)(ws + WS_HIST2);
    u32* gcount  = (u32*)(ws + WS_GCOUNT);
    u32* tick    = (u32*)(ws + WS_TICK);
    u32* gcount2 = (u32*)(ws + WS_GCOUNT2);
    u64* gbuf    = (u64*)(ws + WS_GBUF);
    u64* gbuf2   = (u64*)(ws + WS_GBUF2);
    float4* bbox = (float4*)(ws + WS_BBOX);
    u64* maskT   = (u64*)(ws + WS_MASK);

    hist1_pass<<<dim3(HB, BB), 1024, 0, stream>>>(scores, hist1, hist2, gcount);

    stage_pass<<<dim3(SGB, BB), 256, 0, stream>>>(scores, hist1, hist2, gbuf, gcount);

    refine_pass<<<dim3(D4X, BB), 1024, 0, stream>>>(
        gbuf, gcount, hist1, hist2, rois, reg, gbuf2, bbox, gcount2);

    tail_pass<<<dim3(TLX, BB), 1024, 0, stream>>>(
        gbuf2, bbox, gcount2, maskT, tick, out);
}

// Round 21
// 83.537 us; speedup vs baseline: 2.1244x; 1.0050x over previous
//
#include <hip/hip_runtime.h>
#include <stdint.h>

typedef unsigned int u32;
typedef unsigned long long u64;
typedef unsigned short u16;
typedef unsigned char u8;

#define BB 8
#define NN 8192
#define CC 80
#define KK 1000
#define NC (NN*CC)            // 655360
#define MAXIDX (NC-1)
#define NMS_THR 0.5f
#define SCORE_THR 0.05f
#define MAX_RATIO 4.135166556742356f
#define CLS_OFF 10000.0f
#define CAP 2048
#define NW 16                 // u64 words per mask row
#define HB 8                  // hist1 sub-blocks per batch (1024 thr each)
#define SGB 128               // stage blocks per batch
#define D4X 8                 // refine blocks per batch (1024 thr each)
#define NTILE 136             // lower-triangle 64x64 tiles
#define TLX 9                 // tail blocks per batch (9*16 waves >= 136 tiles)
#define LBUF 1024             // stage per-block staging buffer (u64)
#define GBUFCAP 98304         // per-batch superset capacity (u64)

#define SC_AGENT __HIP_MEMORY_SCOPE_AGENT

// ---- workspace layout (bytes) ----
#define WS_HIST1   0          // BB*HB*2048*4 = 524288 (private slices, plain stores)
#define WS_HIST2   524288     // BB*2048*4 = 65536 (atomic-accumulated; zeroed by hist1)
#define WS_CTRL    589824     // 32 u32: gcount(8), tick(8), gcount2(8), spare(8)
#define WS_GCOUNT  589824
#define WS_TICK    589856
#define WS_GCOUNT2 589888
#define WS_GBUF    589952     // 8*98304*8 = 6291456 -> 6881408
#define WS_GBUF2   6881408    // 8*2048*8 = 131072 -> 7012480
#define WS_BBOX    7012480    // 8*2048*16 = 262144 -> 7274624
#define WS_MASK    7274624    // 8*16*1000*8 = 1024000 -> 8298624

__device__ __forceinline__ u32 mapf(float f) {
    u32 u = __float_as_uint(f);
    return (u & 0x80000000u) ? ~u : (u | 0x80000000u);
}
__device__ __forceinline__ float unmapf(u32 m) {
    u32 u = (m & 0x80000000u) ? (m ^ 0x80000000u) : ~m;
    return __uint_as_float(u);
}

// ---------------- D1: private 11-bit histograms + fold-in zeroing of control bufs -----
__global__ __launch_bounds__(1024) void hist1_pass(const float* __restrict__ scores,
                                                   u32* __restrict__ hist1,
                                                   u32* __restrict__ hist2,
                                                   u32* __restrict__ ctrl /* 32 u32 */) {
    __shared__ u32 lh[2048];
    int b = blockIdx.y, blk = blockIdx.x, t = threadIdx.x;
    for (int i = t; i < 2048; i += 1024) lh[i] = 0;
    if (t < 256) hist2[(b * HB + blk) * 256 + t] = 0u;
    else if (t < 288 && b == 0 && blk == 0) ctrl[t - 256] = 0u;
    __syncthreads();
    const float4* sp = (const float4*)(scores + (size_t)b * NC);
    int nvec = NC / 4;
    for (int v = blk * 1024 + t; v < nvec; v += HB * 1024) {
        float4 s4 = sp[v];
        float ss[4] = {s4.x, s4.y, s4.z, s4.w};
        #pragma unroll
        for (int q = 0; q < 4; ++q) {
            float s = ss[q] > SCORE_THR ? ss[q] : -1.0f;
            atomicAdd(&lh[mapf(s) >> 21], 1u);
        }
    }
    __syncthreads();
    u32* ho = hist1 + ((size_t)b * HB + blk) * 2048;
    for (int i = t; i < 2048; i += 1024) ho[i] = lh[i];
}

// ---- fast digit selects: wave shfl suffix-scan, 2 barriers total ----
__device__ __forceinline__ void sel8_fast(const u32 hv[8], u32 need,
                                          u32* wt, u32* wsuf, u32* bc) {
    int t = threadIdx.x, l = t & 63, w = t >> 6;   // 4 waves
    u32 s = 0;
    #pragma unroll
    for (int q = 0; q < 8; ++q) s += hv[q];
    u32 x = s;
    #pragma unroll
    for (int off = 1; off < 64; off <<= 1) {
        u32 y = __shfl_down(x, off);
        if (l + off < 64) x += y;
    }
    if (l == 0) wt[w] = x;
    __syncthreads();
    if (w == 0) {
        u32 v = (l < 4) ? wt[l] : 0u;
        #pragma unroll
        for (int off = 1; off < 4; off <<= 1) {
            u32 y = __shfl_down(v, off);
            if (l + off < 4) v += y;
        }
        if (l < 4) wsuf[l] = v;
    }
    __syncthreads();
    u32 sufAll = x + ((w < 3) ? wsuf[w + 1] : 0u);
    u32 cumAbove = sufAll - s;
    if (cumAbove < need && sufAll >= need) {
        u32 cum = cumAbove;
        int d = t * 8;
        #pragma unroll
        for (int q = 7; q >= 0; --q) {
            if (cum + hv[q] >= need) { d = t * 8 + q; break; }
            cum += hv[q];
        }
        bc[0] = (u32)d;
        bc[1] = need - cum;
    }
    __syncthreads();
}

__device__ __forceinline__ void sel2_fast(u32 hv0, u32 hv1, u32 need,
                                          u32* wt, u32* wsuf, u32* bc) {
    int t = threadIdx.x, l = t & 63, w = t >> 6;   // 16 waves
    u32 s = hv0 + hv1;
    u32 x = s;
    #pragma unroll
    for (int off = 1; off < 64; off <<= 1) {
        u32 y = __shfl_down(x, off);
        if (l + off < 64) x += y;
    }
    if (l == 0) wt[w] = x;
    __syncthreads();
    if (w == 0) {
        u32 v = (l < 16) ? wt[l] : 0u;
        #pragma unroll
        for (int off = 1; off < 16; off <<= 1) {
            u32 y = __shfl_down(v, off);
            if (l + off < 16) v += y;
        }
        if (l < 16) wsuf[l] = v;
    }
    __syncthreads();
    u32 sufAll = x + ((w < 15) ? wsuf[w + 1] : 0u);
    u32 cumAbove = sufAll - s;
    if (cumAbove < need && sufAll >= need) {
        if (cumAbove + hv1 >= need) { bc[0] = 2u * t + 1u; bc[1] = need - cumAbove; }
        else                        { bc[0] = 2u * t;      bc[1] = need - cumAbove - hv1; }
    }
    __syncthreads();
}

// ---------------- D2: stage d0-superset + build hist2 (bits 20..10 of d0-items) ------
__global__ __launch_bounds__(256) void stage_pass(
    const float* __restrict__ scores, const u32* __restrict__ hist1,
    u32* __restrict__ hist2, u64* __restrict__ gbuf, u32* __restrict__ gcount) {
    __shared__ u64 buf[LBUF];
    __shared__ u32 h2[2048];
    __shared__ u32 wt[4], wsuf[4];
    __shared__ u32 bc[2];
    __shared__ u32 lcnt, lbase;
    int b = blockIdx.y, bx = blockIdx.x, t = threadIdx.x;
    for (int i = t; i < 2048; i += 256) h2[i] = 0;
    if (t == 0) lcnt = 0;
    u32 hv[8];
    {
        const u32* h = hist1 + (size_t)b * HB * 2048;
        #pragma unroll
        for (int q = 0; q < 8; ++q) {
            u32 v = 0;
            #pragma unroll
            for (int sb = 0; sb < HB; ++sb) v += h[sb * 2048 + t * 8 + q];
            hv[q] = v;
        }
    }
    __syncthreads();
    sel8_fast(hv, (u32)KK, wt, wsuf, bc);
    u32 d0 = bc[0];
    const float4* sp = (const float4*)(scores + (size_t)b * NC);
    int nvec = NC / 4;
    for (int v = bx * 256 + t; v < nvec; v += SGB * 256) {
        float4 s4 = sp[v];
        float ss[4] = {s4.x, s4.y, s4.z, s4.w};
        #pragma unroll
        for (int q = 0; q < 4; ++q) {
            float s = ss[q] > SCORE_THR ? ss[q] : -1.0f;
            u32 m = mapf(s);
            u32 top = m >> 21;
            if (top >= d0) {
                u32 p = atomicAdd(&lcnt, 1u);
                if (p < LBUF) {
                    u32 idx = (u32)(v * 4 + q);
                    buf[p] = ((u64)m << 32) | (u64)(MAXIDX - idx);
                }
                if (top == d0) atomicAdd(&h2[(m >> 10) & 0x7FFu], 1u);
            }
        }
    }
    __syncthreads();
    for (int i = t; i < 2048; i += 256)
        if (h2[i]) atomicAdd(&hist2[b * 2048 + i], h2[i]);
    if (t == 0) {
        u32 c = lcnt; if (c > LBUF) c = LBUF;
        lcnt = c;
        lbase = atomicAdd(&gcount[b], c);
    }
    __syncthreads();
    u32 c = lcnt, base = lbase;
    for (u32 i = t; i < c; i += 256) {
        u32 p = base + i;
        if (p < GBUFCAP) gbuf[(size_t)b * GBUFCAP + p] = buf[i];
    }
}

// ---------------- D3: exact 22-bit filter -> gbuf2 + ONE-TIME box decode -> bbox -----
__global__ __launch_bounds__(1024) void refine_pass(
    const u64* __restrict__ gbuf, const u32* __restrict__ gcount,
    const u32* __restrict__ hist1, const u32* __restrict__ hist2,
    const float* __restrict__ rois, const float* __restrict__ reg,
    u64* __restrict__ gbuf2, float4* __restrict__ bbox, u32* __restrict__ gcount2) {
    __shared__ u64 keys[CAP];
    __shared__ u32 wt[16], wsuf[16];
    __shared__ u32 bc[2];
    __shared__ u32 lcnt, lbase;
    int b = blockIdx.y, bx = blockIdx.x, t = threadIdx.x;
    if (t == 0) lcnt = 0;
    u32 hv0 = 0, hv1 = 0;
    {
        const u32* h = hist1 + (size_t)b * HB * 2048;
        #pragma unroll
        for (int sb = 0; sb < HB; ++sb) {
            hv0 += h[sb * 2048 + 2 * t];
            hv1 += h[sb * 2048 + 2 * t + 1];
        }
    }
    __syncthreads();
    sel2_fast(hv0, hv1, (u32)KK, wt, wsuf, bc);
    u32 d0 = bc[0], rem = bc[1];
    __syncthreads();
    sel2_fast(hist2[b * 2048 + 2 * t], hist2[b * 2048 + 2 * t + 1], rem, wt, wsuf, bc);
    u32 thr = ((d0 << 11) | bc[0]) << 10;

    u32 cnt = gcount[b]; if (cnt > GBUFCAP) cnt = GBUFCAP;
    const u64* gb = gbuf + (size_t)b * GBUFCAP;
    u32 chunk = (cnt + D4X - 1) / D4X;
    u32 lo = bx * chunk, hi = lo + chunk; if (hi > cnt) hi = cnt;
    for (u32 i = lo + t; i < hi; i += 1024) {
        u64 key = gb[i];
        if ((u32)(key >> 32) >= thr) {
            u32 p = atomicAdd(&lcnt, 1u);
            if (p < CAP) keys[p] = key;
        }
    }
    __syncthreads();
    if (t == 0) {
        u32 c = lcnt; if (c > CAP) c = CAP;
        lcnt = c;
        lbase = atomicAdd(&gcount2[b], c);      // default atomicAdd = device scope
    }
    __syncthreads();
    u32 c = lcnt, base = lbase;
    for (u32 i = t; i < c; i += 1024) {
        u32 p = base + i;
        if (p < CAP) {
            u64 key = keys[i];
            gbuf2[(size_t)b * CAP + p] = key;
            u32 idx = (u32)MAXIDX - (u32)(key & 0xFFFFFFFFu);
            int n = idx / CC;
            const float* rr = rois + ((size_t)b * NN + n) * 4;
            const float* d  = reg  + ((size_t)b * NN + n) * 4;
            float x1 = rr[0], y1 = rr[1], x2 = rr[2], y2 = rr[3];
            float w = x2 - x1, h = y2 - y1;
            float cx = x1 + 0.5f * w, cy = y1 + 0.5f * h;
            float dx = d[0], dy = d[1];
            float dw = fminf(fmaxf(d[2], -MAX_RATIO), MAX_RATIO);
            float dh = fminf(fmaxf(d[3], -MAX_RATIO), MAX_RATIO);
            float pw = w * expf(dw), ph = h * expf(dh);
            float pcx = cx + dx * w, pcy = cy + dy * h;
            bbox[(size_t)b * CAP + p] = make_float4(
                pcx - 0.5f * pw, pcy - 0.5f * ph, pcx + 0.5f * pw, pcy + 0.5f * ph);
        }
    }
}

// ---------------- D4: fused tail — rank + tables + IoU + LDS-staged NMS + output ----
__global__ __launch_bounds__(1024) void tail_pass(
    const u64* __restrict__ gbuf2, const float4* __restrict__ bboxg,
    const u32* __restrict__ gcount2,
    u64* __restrict__ maskT, u32* __restrict__ tick, float* __restrict__ out) {
    __shared__ union {
        struct {
            u64 keys[CAP];     // 16 KB
            u64 skeys[CAP];    // 16 KB
            u32 cntb[2048];    // 8 KB
            u32 bbase[2048];   // 8 KB
            u32 offb[2048];    // 8 KB
        } s;                   // 56 KB (rank phase)
        u64 tri[NTILE][64];    // 69.6 KB (NMS phase: lower-triangle mask)
    } un;
    __shared__ float4 tb4[KK];     // 16 KB
    __shared__ float4 ob4[KK];     // 16 KB
    __shared__ float ts[KK];       // 4 KB
    __shared__ float tc[KK];       // 4 KB
    __shared__ u8  tv[KK];         // 1 KB
    __shared__ u64 skept[NW];
    __shared__ u32 wt[16], wsuf[16];
    __shared__ u32 redmin[16], redmax[16];
    __shared__ u32 smin_s, smax_s;
    __shared__ int islast;
    int b = blockIdx.y, bx = blockIdx.x, t = threadIdx.x;
    int wv = t >> 6, ln = t & 63;  // 16 waves

    // ---- load compacted candidates + m-range reduce; zero bin arrays ----
    u32 cnt2 = gcount2[b]; if (cnt2 > CAP) cnt2 = CAP;
    un.s.cntb[2 * t] = 0; un.s.cntb[2 * t + 1] = 0;
    u32 mymax = 0u, mymin = 0xFFFFFFFFu;
    for (u32 i = t; i < cnt2; i += 1024) {
        u64 key = gbuf2[(size_t)b * CAP + i];
        un.s.keys[i] = key;
        u32 m = (u32)(key >> 32);
        if (m > mymax) mymax = m;
        if (m < mymin) mymin = m;
    }
    #pragma unroll
    for (int off = 32; off >= 1; off >>= 1) {
        u32 ymx = __shfl_down(mymax, off);
        u32 ymn = __shfl_down(mymin, off);
        if (ymx > mymax) mymax = ymx;
        if (ymn < mymin) mymin = ymn;
    }
    if (ln == 0) { redmax[wv] = mymax; redmin[wv] = mymin; }
    __syncthreads();
    if (t == 0) {
        u32 mx = 0u, mn = 0xFFFFFFFFu;
        #pragma unroll
        for (int i = 0; i < 16; ++i) {
            if (redmax[i] > mx) mx = redmax[i];
            if (redmin[i] < mn) mn = redmin[i];
        }
        smax_s = mx; smin_s = mn;
    }
    __syncthreads();
    u32 smin = smin_s;
    u32 range = smax_s - smin;
    u32 SH = (range >= 2048u) ? (32u - (u32)__clz((int)range) - 11u) : 0u;

    // ---- bin histogram (one atomic per key) ----
    for (u32 i = t; i < cnt2; i += 1024) {
        u32 m = (u32)(un.s.keys[i] >> 32);
        atomicAdd(&un.s.cntb[(m - smin) >> SH], 1u);
    }
    __syncthreads();

    // ---- suffix-scan -> bbase[bin] = #keys in strictly higher bins; zero offb ----
    {
        u32 c0b = un.s.cntb[2 * t], c1b = un.s.cntb[2 * t + 1];
        u32 s = c0b + c1b;
        u32 x = s;
        #pragma unroll
        for (int off = 1; off < 64; off <<= 1) {
            u32 y = __shfl_down(x, off);
            if (ln + off < 64) x += y;
        }
        if (ln == 0) wt[wv] = x;
        __syncthreads();
        if (wv == 0) {
            u32 v = (ln < 16) ? wt[ln] : 0u;
            #pragma unroll
            for (int off = 1; off < 16; off <<= 1) {
                u32 y = __shfl_down(v, off);
                if (ln + off < 16) v += y;
            }
            if (ln < 16) wsuf[ln] = v;
        }
        __syncthreads();
        u32 sufAll = x + ((wv < 15) ? wsuf[wv + 1] : 0u);
        un.s.bbase[2 * t]     = sufAll - c0b;
        un.s.bbase[2 * t + 1] = sufAll - s;
        un.s.offb[2 * t] = 0; un.s.offb[2 * t + 1] = 0;
    }
    __syncthreads();

    // ---- scatter into bin-ordered skeys ----
    for (u32 i = t; i < cnt2; i += 1024) {
        u64 key = un.s.keys[i];
        u32 bin = ((u32)(key >> 32) - smin) >> SH;
        u32 p = un.s.bbase[bin] + atomicAdd(&un.s.offb[bin], 1u);
        un.s.skeys[p] = key;
    }
    __syncthreads();

    // ---- rank (iterating original index i -> bbox[i] stays linear) + fill tables ----
    for (u32 i = t; i < cnt2; i += 1024) {
        u64 key = un.s.keys[i];
        u32 bin = ((u32)(key >> 32) - smin) >> SH;
        u32 lo = un.s.bbase[bin], hi = lo + un.s.cntb[bin];
        u32 r = lo;
        for (u32 q = lo; q < hi; ++q)
            r += (un.s.skeys[q] > key) ? 1u : 0u;
        if (r < KK) {
            float4 bx = bboxg[(size_t)b * CAP + i];
            u32 m = (u32)(key >> 32);
            u32 idx = (u32)MAXIDX - (u32)(key & 0xFFFFFFFFu);
            float score = unmapf(m);
            float cf = (float)((int)(idx % CC) + 1);
            tb4[r] = bx;
            ts[r] = score; tc[r] = cf; tv[r] = (score > SCORE_THR) ? 1 : 0;
            float off = cf * CLS_OFF;
            ob4[r] = make_float4(bx.x + off, bx.y + off, bx.z + off, bx.w + off);
        }
    }
    // filler rows [cnt2, KK)
    for (u32 r = cnt2 + t; r < KK; r += 1024) {
        ts[r] = -1.0f; tc[r] = 0.0f; tv[r] = 0;
        tb4[r] = make_float4(0.f, 0.f, 0.f, 0.f);
        ob4[r] = make_float4(0.f, 0.f, 0.f, 0.f);
    }
    __syncthreads();

    // ---- IoU: one 64x64 lower-triangle tile per wave; T = bx*16 + wv ----
    {
        int T = bx * 16 + wv;
        if (T < NTILE) {
            int ib = (int)((sqrtf(8.0f * (float)T + 1.0f) - 1.0f) * 0.5f);
            while ((ib + 1) * (ib + 2) / 2 <= T) ++ib;
            while (ib * (ib + 1) / 2 > T) --ib;
            int jbk = T - ib * (ib + 1) / 2;
            int i = ib * 64 + ln;
            if (i < KK) {
                float4 o = ob4[i];
                float x1 = o.x, y1 = o.y, x2 = o.z, y2 = o.w;
                float ai = (x2 - x1) * (y2 - y1);
                u64 bits = 0;
                int j0 = jbk * 64;
                int jmax = min(64, KK - j0);
                for (int jj = 0; jj < jmax; ++jj) {
                    float4 bj = ob4[j0 + jj];
                    float aj = (bj.z - bj.x) * (bj.w - bj.y);
                    float iw = fmaxf(fminf(x2, bj.z) - fmaxf(x1, bj.x), 0.0f);
                    float ih = fmaxf(fminf(y2, bj.w) - fmaxf(y1, bj.y), 0.0f);
                    float inter = iw * ih;
                    float iou = inter / (ai + aj - inter + 1e-9f);
                    if (iou > NMS_THR) bits |= (1ull << jj);
                }
                __hip_atomic_store(&maskT[((size_t)b * NW + jbk) * KK + i], bits,
                                   __ATOMIC_RELAXED, SC_AGENT);
            }
        }
    }
    __syncthreads();
    if (t == 0) {
        u32 tk = __hip_atomic_fetch_add(&tick[b], 1u, __ATOMIC_ACQ_REL, SC_AGENT);
        islast = (tk == (u32)(TLX - 1)) ? 1 : 0;
    }
    __syncthreads();
    if (!islast) return;

    // ---- last block: cooperative stage of lower-triangle mask -> LDS (full MLP) ----
    // (sort arrays in the union are dead now; tri[] overlays them)
    for (u32 g = t; g < (u32)(NTILE * 64); g += 1024) {
        u32 T = g >> 6, l2 = g & 63;
        u32 W = (u32)((sqrtf(8.0f * (float)T + 1.0f) - 1.0f) * 0.5f);
        while ((W + 1) * (W + 2) / 2 <= T) ++W;
        while (W * (W + 1) / 2 > T) --W;
        u32 w = T - W * (W + 1) / 2;
        u32 i = W * 64 + l2;
        u64 v = 0;
        if (i < (u32)KK)
            v = __hip_atomic_load(&maskT[((size_t)b * NW + w) * KK + i],
                                  __ATOMIC_RELAXED, SC_AGENT);
        un.tri[T][l2] = v;
    }
    __syncthreads();

    // ---- ballot fixed-point NMS (first wave) from LDS ----
    if (t < 64) {
        u64 keptW[NW];
        #pragma unroll
        for (int W = 0; W < NW; ++W) {
            int base = W * (W + 1) / 2;
            int i = W * 64 + ln;
            bool valid = (i < KK) && (tv[i] != 0);
            u64 ext = 0;
            for (int w = 0; w < W; ++w) ext |= keptW[w] & un.tri[base + w][ln];
            u64 rowW = un.tri[base + W][ln];
            bool cand = valid && (ext == 0ull);
            u64 m_self = rowW & ((1ull << ln) - 1ull);
            u64 kept = __ballot(cand);
            while (true) {
                u64 k2 = __ballot(cand && ((kept & m_self) == 0ull));
                if (k2 == kept) break;
                kept = k2;
            }
            keptW[W] = kept;
            if (ln == 0) skept[W] = kept;
        }
    }
    __syncthreads();

    // ---- masked output straight from LDS ----
    for (int kk = t; kk < KK; kk += 1024) {
        size_t o = (size_t)b * KK + kk;
        float kf = (float)((skept[kk >> 6] >> (kk & 63)) & 1ull);
        float4 bb = tb4[kk];
        float* op = out + o * 7;
        op[0] = bb.x * kf; op[1] = bb.y * kf;
        op[2] = bb.z * kf; op[3] = bb.w * kf;
        op[4] = ts[kk] * kf; op[5] = tc[kk] * kf; op[6] = kf;
    }
}

extern "C" void kernel_launch(void* const* d_in, const int* in_sizes, int n_in,
                              void* d_out, int out_size, void* d_ws, size_t ws_size,
                              hipStream_t stream) {
    const float* rois   = (const float*)d_in[0];   // (B,N,4)
    const float* scores = (const float*)d_in[1];   // (B*N,C,1,1) == (B, N*C)
    const float* reg    = (const float*)d_in[2];   // (B*N,4,1,1)
    float* out = (float*)d_out;

    char* ws = (char*)d_ws;
    u32* hist1   = (u32*)(ws + WS_HIST1);
    u32* hist2   = (u32*)(ws + WS_HIST2);
    u32* gcount  = (u32*)(ws + WS_GCOUNT);
    u32* tick    = (u32*)(ws + WS_TICK);
    u32* gcount2 = (u32*)(ws + WS_GCOUNT2);
    u64* gbuf    = (u64*)(ws + WS_GBUF);
    u64* gbuf2   = (u64*)(ws + WS_GBUF2);
    float4* bbox = (float4*)(ws + WS_BBOX);
    u64* maskT   = (u64*)(ws + WS_MASK);

    hist1_pass<<<dim3(HB, BB), 1024, 0, stream>>>(scores, hist1, hist2, gcount);

    stage_pass<<<dim3(SGB, BB), 256, 0, stream>>>(scores, hist1, hist2, gbuf, gcount);

    refine_pass<<<dim3(D4X, BB), 1024, 0, stream>>>(
        gbuf, gcount, hist1, hist2, rois, reg, gbuf2, bbox, gcount2);

    tail_pass<<<dim3(TLX, BB), 1024, 0, stream>>>(
        gbuf2, bbox, gcount2, maskT, tick, out);
}